// Round 3
// baseline (759.680 us; speedup 1.0000x reference)
//
#include <hip/hip_runtime.h>
#include <hip/hip_bf16.h>
#include <math.h>

typedef __bf16 bf16x8 __attribute__((ext_vector_type(8)));
typedef __bf16 bf16x4 __attribute__((ext_vector_type(4)));
typedef float f32x4 __attribute__((ext_vector_type(4)));

#define MFMA16(a,b,c) __builtin_amdgcn_mfma_f32_16x16x32_bf16(a,b,c,0,0,0)

static constexpr int Nn = 48, Hh = 256;
static constexpr int Ee = 2256, BT = 64;
static constexpr int ETILE = 128, NTILES = 18;         // 18*128 = 2304 >= 2256
static constexpr float BN_RS = 0.9999950000374998f;     // 1/sqrt(1+1e-5)

// ---- ws layout (bytes), total ~5.0 MB ----
static constexpr size_t WS_WF  = 0;        // 4 mats bf16 frag-linear: 524288
static constexpr size_t WS_RRA = 524288;   // rel_rec^T A-frags: 18*4*3*64*8 bf16 = 221184
static constexpr size_t WS_TN  = 745472;   // node transposed weights: 268320 f32 = 1073280
static constexpr size_t WS_AGG = 1818752;  // g_agg [64][48][256] f32 = 3145728

// ---- LDS layout (bytes) ----
static constexpr int LDS_ACT  = 0;        // [128][512B] bf16 act, swizzled; reused as agg B-frags
static constexpr int LDS_WSG  = 65536;    // 2 x 16384 double-buffered weight chunk
static constexpr int LDS_XS   = 98304;    // 192 f32
static constexpr int LDS_PM   = 99072;    // pm[8][128] f32 (k-major, conflict-free)
static constexpr int LDS_RT   = 103168;   // [128][2] f32
static constexpr int LDS_BIAS = 104192;   // 256 f32 (per-GEMM bias)
static constexpr int LDS_FB   = 105216;   // 256 f32 (fc1 bias)
static constexpr int LDS_SC   = 106240;   // 256 f32
static constexpr int LDS_SBE  = 107264;   // 256 f32
static constexpr int LDS_EDGE_BYTES = 108288;

__device__ __forceinline__ float eluf(float v) { return v > 0.f ? v : __expf(v) - 1.f; }

// row-swizzled byte offset inside the [128][512B] activation buffer
__device__ __forceinline__ int aoff(int e, int colbyte) {
  return e * 512 + (colbyte ^ ((e & 7) << 4));
}

// K=256 GEMM: 32 edges (2 m-tiles) x 128 cols (8 n-tiles) per wave.
// A from swizzled LDS act (wave-private rows); B frag-linear in global,
// double-buffer staged to LDS, 1 barrier per K-chunk, chunk+2 reg prefetch.
__device__ __forceinline__ void gemm256(char* smem, const __bf16* wfmat,
                                        const float* bsrc, const float* sc_src,
                                        const float* be_src,
                                        int tid, int lane, int m0, int n0b,
                                        f32x4 acc[2][8]) {
  const uint4* wsrc = (const uint4*)wfmat;
  uint4 sa[2], sb[2];
  sa[0] = wsrc[tid];        sb[0] = wsrc[512 + tid];
  sa[1] = wsrc[1024 + tid]; sb[1] = wsrc[1536 + tid];
  uint4* buf0 = (uint4*)(smem + LDS_WSG);
  buf0[tid] = sa[0]; buf0[512 + tid] = sb[0];
  __syncthreads();  // chunk0 staged; all waves past previous phase's LDS reads
  float* bias = (float*)(smem + LDS_BIAS);
  if (tid < Hh) {
    bias[tid] = bsrc[tid];
    if (sc_src != nullptr) {
      ((float*)(smem + LDS_SC))[tid] = sc_src[tid] * BN_RS;
      ((float*)(smem + LDS_SBE))[tid] = be_src[tid];
    }
  }
  const int kgb = (lane >> 4) * 16;  // A k-group byte offset
#pragma unroll
  for (int kt = 0; kt < 8; ++kt) {
    const char* bbase = smem + LDS_WSG + (kt & 1) * 16384;
    const int r0 = m0 + (lane & 15), r1 = r0 + 16;
    bf16x8 af0 = *(const bf16x8*)(smem + LDS_ACT + r0 * 512 + ((kt * 64 + kgb) ^ ((r0 & 7) << 4)));
    bf16x8 af1 = *(const bf16x8*)(smem + LDS_ACT + r1 * 512 + ((kt * 64 + kgb) ^ ((r1 & 7) << 4)));
#pragma unroll
    for (int nt = 0; nt < 8; ++nt) {
      bf16x8 bfr = *(const bf16x8*)(bbase + ((n0b + nt) * 64 + lane) * 16);
      acc[0][nt] = MFMA16(af0, bfr, acc[0][nt]);
      acc[1][nt] = MFMA16(af1, bfr, acc[1][nt]);
    }
    if (kt < 7) {
      uint4* dst = (uint4*)(smem + LDS_WSG + ((kt + 1) & 1) * 16384);
      dst[tid] = sa[(kt + 1) & 1]; dst[512 + tid] = sb[(kt + 1) & 1];
      if (kt < 6) {
        sa[kt & 1] = wsrc[(kt + 2) * 1024 + tid];
        sb[kt & 1] = wsrc[(kt + 2) * 1024 + 512 + tid];
      }
    }
    __syncthreads();
  }
}

__global__ __launch_bounds__(512, 2)
void edge_kernel(const float* __restrict__ x, const float* __restrict__ rel_rec,
                 const float* __restrict__ rel_send, const float* __restrict__ rel_type,
                 const float* __restrict__ mf1_w, const float* __restrict__ mf1_b,
                 const float* __restrict__ mf2_b, const float* __restrict__ at1_b1,
                 const float* __restrict__ at1_b2, const float* __restrict__ at1_g,
                 const float* __restrict__ at1_be, const __bf16* __restrict__ wf,
                 const __bf16* __restrict__ rra, float* __restrict__ g_agg) {
  extern __shared__ char smem[];
  float* xs = (float*)(smem + LDS_XS);
  float* pm = (float*)(smem + LDS_PM);
  float* rt = (float*)(smem + LDS_RT);
  float* bias = (float*)(smem + LDS_BIAS);
  float* fb = (float*)(smem + LDS_FB);
  float* sc = (float*)(smem + LDS_SC);
  float* sbe = (float*)(smem + LDS_SBE);

  const int tid = threadIdx.x;
  const int lane = tid & 63;
  const int wv = tid >> 6;
  const int wvM = wv & 3, wvN = wv >> 2;
  const int m0 = wvM * 32, n0 = wvN * 128, n0b = wvN * 8;
  const int slice = blockIdx.x >> 2;
  const int split = blockIdx.x & 3;
  const int t_begin = (split < 2) ? split * 5 : 10 + (split - 2) * 4;
  const int t_cnt = (split < 2) ? 5 : 4;

  if (tid < Nn * 4) xs[tid] = x[slice * Nn * 4 + tid];

  // cross-tile register accumulator for agg GEMM
  f32x4 ag[3][2];
#pragma unroll
  for (int mt2 = 0; mt2 < 3; ++mt2)
#pragma unroll
    for (int ntl = 0; ntl < 2; ++ntl) ag[mt2][ntl] = (f32x4){0.f, 0.f, 0.f, 0.f};

  for (int tt = 0; tt < t_cnt; ++tt) {
    const int tile = t_begin + tt;
    const int e0 = tile * ETILE;
    const int ne = min(ETILE, Ee - e0);

    if (tid < ETILE * 2) {
      int e = tid >> 1, i = tid & 1;
      rt[tid] = (e < ne) ? rel_type[((size_t)slice * Ee + e0 + e) * 2 + i] : 0.f;
    }
    __syncthreads();  // xs (first tile) + rt visible

    // pre_msg k-major: pm[c][e], c: 0-3 senders, 4-7 receivers
#pragma unroll
    for (int p = 0; p < 2; ++p) {
      int t = p * 512 + tid;
      int c = t >> 7, e = t & 127;
      float s = 0.f;
      if (e < ne) {
        const float* rel = ((c < 4) ? rel_send : rel_rec) + (size_t)(e0 + e) * Nn;
        int f = c & 3;
#pragma unroll
        for (int n = 0; n < Nn; ++n) s += rel[n] * xs[n * 4 + f];
      }
      pm[c * 128 + e] = s;
    }

    f32x4 allm[2][8];
#pragma unroll
    for (int mt = 0; mt < 2; ++mt)
#pragma unroll
      for (int nt = 0; nt < 8; ++nt) allm[mt][nt] = (f32x4){0.f, 0.f, 0.f, 0.f};

    for (int ty = 0; ty < 2; ++ty) {
      // stage mf1[ty] into wsg buf1 (disjoint from gemm prologue's buf0) + fc1 bias
      ((uint4*)(smem + LDS_WSG + 16384))[tid] = ((const uint4*)(mf1_w + ty * 2048))[tid];
      if (tid < Hh) fb[tid] = mf1_b[ty * Hh + tid];
      __syncthreads();  // also covers pm writes
      // fc1 (K=8) -> act (bf16, swizzled)
      const float* wsf = (const float*)(smem + LDS_WSG + 16384);
#pragma unroll
      for (int it = 0; it < 8; ++it) {
        int t = it * 512 + tid;
        int e = t & 127, hc = t >> 7;
        float pmr[8];
#pragma unroll
        for (int k = 0; k < 8; ++k) pmr[k] = pm[k * 128 + e];
        bf16x8 pv;
#pragma unroll
        for (int j = 0; j < 8; ++j) {
          int h = hc * 8 + j;
          float s = fb[h];
#pragma unroll
          for (int k = 0; k < 8; ++k) s = fmaf(pmr[k], wsf[h * 8 + k], s);
          pv[j] = (__bf16)fmaxf(s, 0.f);
        }
        *(bf16x8*)(smem + LDS_ACT + aoff(e, hc * 16)) = pv;
      }
      f32x4 acc[2][8];
#pragma unroll
      for (int mt = 0; mt < 2; ++mt)
#pragma unroll
        for (int nt = 0; nt < 8; ++nt) acc[mt][nt] = (f32x4){0.f, 0.f, 0.f, 0.f};
      gemm256(smem, wf + (size_t)ty * 65536, mf2_b + ty * Hh, nullptr, nullptr,
              tid, lane, m0, n0b, acc);
#pragma unroll
      for (int mt = 0; mt < 2; ++mt) {
        float rtv[4];
#pragma unroll
        for (int r = 0; r < 4; ++r) rtv[r] = rt[(m0 + mt * 16 + (lane >> 4) * 4 + r) * 2 + ty];
#pragma unroll
        for (int nt = 0; nt < 8; ++nt) {
          float bb = bias[n0 + nt * 16 + (lane & 15)];
#pragma unroll
          for (int r = 0; r < 4; ++r)
            allm[mt][nt][r] += fmaxf(acc[mt][nt][r] + bb, 0.f) * rtv[r];
        }
      }
    }

    // all_msgs -> act in place (each wave writes its own rows x its own cols)
#pragma unroll
    for (int mt = 0; mt < 2; ++mt)
#pragma unroll
      for (int nt = 0; nt < 8; ++nt)
#pragma unroll
        for (int r = 0; r < 4; ++r) {
          int e = m0 + mt * 16 + (lane >> 4) * 4 + r;
          int cb = (n0 + nt * 16 + (lane & 15)) * 2;
          *(__bf16*)(smem + LDS_ACT + aoff(e, cb)) = (__bf16)allm[mt][nt][r];
        }

    // at1 layer 1: act -> elu -> act (in place)
    {
      f32x4 acc[2][8];
#pragma unroll
      for (int mt = 0; mt < 2; ++mt)
#pragma unroll
        for (int nt = 0; nt < 8; ++nt) acc[mt][nt] = (f32x4){0.f, 0.f, 0.f, 0.f};
      gemm256(smem, wf + (size_t)2 * 65536, at1_b1, nullptr, nullptr,
              tid, lane, m0, n0b, acc);
#pragma unroll
      for (int mt = 0; mt < 2; ++mt)
#pragma unroll
        for (int nt = 0; nt < 8; ++nt) {
          float bb = bias[n0 + nt * 16 + (lane & 15)];
#pragma unroll
          for (int r = 0; r < 4; ++r) {
            int e = m0 + mt * 16 + (lane >> 4) * 4 + r;
            int cb = (n0 + nt * 16 + (lane & 15)) * 2;
            *(__bf16*)(smem + LDS_ACT + aoff(e, cb)) = (__bf16)eluf(acc[mt][nt][r] + bb);
          }
        }
    }

    // at1 layer 2: act -> elu*sc+be -> agg B-frags (overwrites act region)
    {
      f32x4 acc[2][8];
#pragma unroll
      for (int mt = 0; mt < 2; ++mt)
#pragma unroll
        for (int nt = 0; nt < 8; ++nt) acc[mt][nt] = (f32x4){0.f, 0.f, 0.f, 0.f};
      gemm256(smem, wf + (size_t)3 * 65536, at1_b2, at1_g, at1_be,
              tid, lane, m0, n0b, acc);
      // after final kt sync all act reads are done -> safe to overwrite with B-frags
      const int j0 = ((lane >> 4) & 1) * 4;
      const int lh_base = (lane >> 4) >> 1;
#pragma unroll
      for (int mt = 0; mt < 2; ++mt) {
        const int lane_hi = mt * 2 + lh_base;
#pragma unroll
        for (int nt = 0; nt < 8; ++nt) {
          int col = n0 + nt * 16 + (lane & 15);
          float bb = bias[col], s1 = sc[col], s2 = sbe[col];
          bf16x4 pk;
#pragma unroll
          for (int r = 0; r < 4; ++r)
            pk[r] = (__bf16)(eluf(acc[mt][nt][r] + bb) * s1 + s2);
          int addr = ((((wvM * 16) + (n0b + nt)) * 64 + lane_hi * 16 + (lane & 15)) * 8 + j0) * 2;
          *(bf16x4*)(smem + LDS_ACT + addr) = pk;
        }
      }
    }
    __syncthreads();  // B-frags visible

    // aggregation GEMM: ag += rel_rec[tile]^T @ h_edges  (M=48, N=256, K=128)
    const bf16x8* rraw = (const bf16x8*)rra + (size_t)tile * 768;
#pragma unroll
    for (int kt2 = 0; kt2 < 4; ++kt2) {
      bf16x8 b0 = *(const bf16x8*)(smem + LDS_ACT + ((kt2 * 16 + wv * 2 + 0) * 64 + lane) * 16);
      bf16x8 b1 = *(const bf16x8*)(smem + LDS_ACT + ((kt2 * 16 + wv * 2 + 1) * 64 + lane) * 16);
#pragma unroll
      for (int mt2 = 0; mt2 < 3; ++mt2) {
        bf16x8 a = rraw[(kt2 * 3 + mt2) * 64 + lane];
        ag[mt2][0] = MFMA16(a, b0, ag[mt2][0]);
        ag[mt2][1] = MFMA16(a, b1, ag[mt2][1]);
      }
    }
    __syncthreads();  // agg reads of ACT done before next tile's fc1 overwrites
  }

  // one atomic pass per block (4 blocks contribute per slice)
  float* dst = g_agg + (size_t)slice * Nn * Hh;
#pragma unroll
  for (int mt2 = 0; mt2 < 3; ++mt2)
#pragma unroll
    for (int ntl = 0; ntl < 2; ++ntl) {
      int h = (wv * 2 + ntl) * 16 + (lane & 15);
#pragma unroll
      for (int r = 0; r < 4; ++r) {
        int n = mt2 * 16 + (lane >> 4) * 4 + r;
        atomicAdd(dst + n * Hh + h, ag[mt2][ntl][r]);
      }
    }
}

// 4 weight matrices [256][256] fp32 -> bf16 MFMA B-fragment-linear
__global__ void prep_frag(const float* __restrict__ mf2_w, const float* __restrict__ at1_w1,
                          const float* __restrict__ at1_w2, __bf16* __restrict__ wfdst) {
  int id = blockIdx.x * 256 + threadIdx.x;  // 32768 total
  int mat = id >> 13, r = id & 8191;
  int kt = r >> 10, q = r & 1023, nt = q >> 6, l = q & 63;
  int row = nt * 16 + (l & 15), col = kt * 32 + (l >> 4) * 8;
  const float* src = (mat == 0) ? mf2_w : (mat == 1) ? (mf2_w + 65536)
                   : (mat == 2) ? at1_w1 : at1_w2;
  const float* p = src + row * 256 + col;
  __bf16* d = wfdst + (size_t)mat * 65536 + ((size_t)(kt * 16 + nt) * 64 + l) * 8;
#pragma unroll
  for (int j = 0; j < 8; ++j) d[j] = (__bf16)p[j];
}

// rel_rec^T per-tile bf16 A-fragments: rra[tile][kt2][mt2][lane][8]
__global__ void prep_rra(const float* __restrict__ rel_rec, __bf16* __restrict__ rra) {
  int id = blockIdx.x * 256 + threadIdx.x;  // 54*256 = 13824
  int tile = id / 768, r = id % 768;
  int kt2 = r / 192, r2 = r % 192, mt2 = r2 >> 6, l = r2 & 63;
  int ebase = tile * 128 + kt2 * 32 + (l >> 4) * 8;
  int n = mt2 * 16 + (l & 15);
  bf16x8 v;
#pragma unroll
  for (int j = 0; j < 8; ++j) {
    int e = ebase + j;
    v[j] = (__bf16)((e < Ee) ? rel_rec[(size_t)e * Nn + n] : 0.f);
  }
  ((bf16x8*)rra)[id] = v;
}

// transpose node-side weights (fp32) for coalesced lane reads
__global__ void prep_node(const float* __restrict__ at5_w1, const float* __restrict__ at5_w2,
                          const float* __restrict__ o1_w, const float* __restrict__ o2_w,
                          const float* __restrict__ o3_w, float* __restrict__ ws) {
  int id = blockIdx.x * 256 + threadIdx.x;
  float* T1 = ws;
  float* T2 = T1 + 67600;
  float* To1 = T2 + 67600;
  float* To2 = To1 + 66560;
  float* To3 = To2 + 65536;
  if (id < 67600) { int o = id % 260, k = id / 260; T1[k * 260 + o] = at5_w1[o * 260 + k]; return; }
  id -= 67600;
  if (id < 67600) { int o = id % 260, k = id / 260; T2[k * 260 + o] = at5_w2[o * 260 + k]; return; }
  id -= 67600;
  if (id < 66560) { int o = id & 255, k = id >> 8; To1[k * 256 + o] = o1_w[o * 260 + k]; return; }
  id -= 66560;
  if (id < 65536) { int o = id & 255, k = id >> 8; To2[k * 256 + o] = o2_w[o * 256 + k]; return; }
  id -= 65536;
  if (id < 1024) { int f = id & 3, k = id >> 2; To3[k * 4 + f] = o3_w[f * 256 + k]; }
}

__global__ __launch_bounds__(256, 4)
void node_kernel(const float* __restrict__ g_agg, const float* __restrict__ x,
                 const float* __restrict__ T1, const float* __restrict__ T2,
                 const float* __restrict__ To1, const float* __restrict__ To2,
                 const float* __restrict__ To3, const float* __restrict__ at5_b1,
                 const float* __restrict__ at5_b2, const float* __restrict__ at5_g,
                 const float* __restrict__ at5_be, const float* __restrict__ o1_b,
                 const float* __restrict__ o2_b, const float* __restrict__ o3_b,
                 float* __restrict__ out) {
  __shared__ float bufA[12 * 264], bufB[12 * 264], xres[12 * 4];
  const int tid = threadIdx.x;
  const int slice = blockIdx.x >> 2, rg = blockIdx.x & 3;
  const int n0 = rg * 12;
  for (int t = tid; t < 12 * 256; t += 256) {
    int r = t >> 8, h = t & 255;
    bufA[r * 264 + h] = g_agg[(size_t)slice * 12288 + (size_t)(n0 + r) * 256 + h];
  }
  if (tid < 48) {
    int r = tid >> 2, f = tid & 3;
    float v = x[(size_t)slice * 192 + (n0 + r) * 4 + f];
    bufA[r * 264 + 256 + f] = v;
    xres[tid] = v;
  }
  __syncthreads();

  auto layer = [&](const float* WT, const float* bsrc, const float* in, float* outb,
                   int K, int O, int act, const float* gsc, const float* gbe) {
    for (int o = tid; o < O; o += 256) {
      float a[12];
      float bb = bsrc[o];
#pragma unroll
      for (int r = 0; r < 12; ++r) a[r] = bb;
      for (int k = 0; k < K; ++k) {
        float w = WT[k * O + o];
#pragma unroll
        for (int r = 0; r < 12; ++r) a[r] = fmaf(in[r * 264 + k], w, a[r]);
      }
      float scv = 1.f, bev = 0.f;
      if (act == 2) { scv = gsc[o] * BN_RS; bev = gbe[o]; }
#pragma unroll
      for (int r = 0; r < 12; ++r) {
        float v = a[r];
        v = (act == 0) ? fmaxf(v, 0.f) : eluf(v);
        if (act == 2) v = v * scv + bev;
        outb[r * 264 + o] = v;
      }
    }
    __syncthreads();
  };

  layer(T1, at5_b1, bufA, bufB, 260, 260, 1, nullptr, nullptr);
  layer(T2, at5_b2, bufB, bufA, 260, 260, 2, at5_g, at5_be);
  layer(To1, o1_b, bufA, bufB, 260, 256, 0, nullptr, nullptr);
  layer(To2, o2_b, bufB, bufA, 256, 256, 0, nullptr, nullptr);
  if (tid < 48) {
    int r = tid >> 2, f = tid & 3;
    float s = o3_b[f];
    for (int k = 0; k < 256; ++k) s = fmaf(bufA[r * 264 + k], To3[k * 4 + f], s);
    out[(size_t)slice * 192 + (n0 + r) * 4 + f] = xres[tid] + s;
  }
}

extern "C" void kernel_launch(void* const* d_in, const int* in_sizes, int n_in,
                              void* d_out, int out_size, void* d_ws, size_t ws_size,
                              hipStream_t stream) {
  const float* x = (const float*)d_in[0];
  const float* rel_rec = (const float*)d_in[1];
  const float* rel_send = (const float*)d_in[2];
  const float* rel_type = (const float*)d_in[3];
  const float* mf1_w = (const float*)d_in[4];
  const float* mf1_b = (const float*)d_in[5];
  const float* mf2_w = (const float*)d_in[6];
  const float* mf2_b = (const float*)d_in[7];
  const float* at1_w1 = (const float*)d_in[8];
  const float* at1_b1 = (const float*)d_in[9];
  const float* at1_w2 = (const float*)d_in[10];
  const float* at1_b2 = (const float*)d_in[11];
  const float* at1_g = (const float*)d_in[12];
  const float* at1_be = (const float*)d_in[13];
  const float* at5_w1 = (const float*)d_in[14];
  const float* at5_b1 = (const float*)d_in[15];
  const float* at5_w2 = (const float*)d_in[16];
  const float* at5_b2 = (const float*)d_in[17];
  const float* at5_g = (const float*)d_in[18];
  const float* at5_be = (const float*)d_in[19];
  const float* o1_w = (const float*)d_in[20];
  const float* o1_b = (const float*)d_in[21];
  const float* o2_w = (const float*)d_in[22];
  const float* o2_b = (const float*)d_in[23];
  const float* o3_w = (const float*)d_in[24];
  const float* o3_b = (const float*)d_in[25];

  char* ws = (char*)d_ws;
  __bf16* wf = (__bf16*)(ws + WS_WF);
  __bf16* rra = (__bf16*)(ws + WS_RRA);
  float* tnode = (float*)(ws + WS_TN);
  float* g_agg = (float*)(ws + WS_AGG);

  hipMemsetAsync(g_agg, 0, (size_t)BT * Nn * Hh * 4, stream);
  prep_frag<<<128, 256, 0, stream>>>(mf2_w, at1_w1, at1_w2, wf);
  prep_rra<<<54, 256, 0, stream>>>(rel_rec, rra);
  prep_node<<<1049, 256, 0, stream>>>(at5_w1, at5_w2, o1_w, o2_w, o3_w, tnode);

  hipFuncSetAttribute((const void*)edge_kernel,
                      hipFuncAttributeMaxDynamicSharedMemorySize, LDS_EDGE_BYTES);
  edge_kernel<<<BT * 4, 512, LDS_EDGE_BYTES, stream>>>(
      x, rel_rec, rel_send, rel_type, mf1_w, mf1_b, mf2_b, at1_b1, at1_b2,
      at1_g, at1_be, wf, rra, g_agg);

  node_kernel<<<256, 256, 0, stream>>>(g_agg, x, tnode, tnode + 67600,
                                       tnode + 135200, tnode + 201760, tnode + 267296,
                                       at5_b1, at5_b2, at5_g, at5_be,
                                       o1_b, o2_b, o3_b, (float*)d_out);
}

// Round 4
// 759.245 us; speedup vs baseline: 1.0006x; 1.0006x over previous
//
#include <hip/hip_runtime.h>
#include <hip/hip_bf16.h>
#include <math.h>

typedef __bf16 bf16x8 __attribute__((ext_vector_type(8)));
typedef __bf16 bf16x4 __attribute__((ext_vector_type(4)));
typedef float f32x4 __attribute__((ext_vector_type(4)));

#define MFMA16(a,b,c) __builtin_amdgcn_mfma_f32_16x16x32_bf16(a,b,c,0,0,0)

static constexpr int Nn = 48, Hh = 256;
static constexpr int Ee = 2256, BT = 64;
static constexpr int ETILE = 128, NTILES = 18;         // 18*128 = 2304 >= 2256
static constexpr float BN_RS = 0.9999950000374998f;     // 1/sqrt(1+1e-5)

// ---- ws layout (bytes), total ~5.0 MB ----
static constexpr size_t WS_WF  = 0;        // 4 mats bf16 frag-linear: 524288
static constexpr size_t WS_RRA = 524288;   // rel_rec^T A-frags: 18*4*3*64*8 bf16 = 221184
static constexpr size_t WS_TN  = 745472;   // node transposed weights: 268320 f32 = 1073280
static constexpr size_t WS_AGG = 1818752;  // g_agg [64][48][256] f32 = 3145728

// ---- LDS layout (bytes) ----
static constexpr int LDS_ACT  = 0;        // [128][512B] bf16 act, swizzled; reused as agg B-frags
static constexpr int LDS_WSG  = 65536;    // 2 x 16384 double-buffered weight chunk
static constexpr int LDS_XS   = 98304;    // 192 f32
static constexpr int LDS_PM   = 99072;    // pm[8][128] f32 (k-major, conflict-free)
static constexpr int LDS_RT   = 103168;   // [128][2] f32
static constexpr int LDS_BIAS = 104192;   // 256 f32 (per-GEMM bias)
static constexpr int LDS_FB   = 105216;   // 256 f32 (fc1 bias)
static constexpr int LDS_SC   = 106240;   // 256 f32
static constexpr int LDS_SBE  = 107264;   // 256 f32
static constexpr int LDS_EDGE_BYTES = 108288;

__device__ __forceinline__ float eluf(float v) { return v > 0.f ? v : __expf(v) - 1.f; }

// row-swizzled byte offset inside the [128][512B] activation buffer
__device__ __forceinline__ int aoff(int e, int colbyte) {
  return e * 512 + (colbyte ^ ((e & 7) << 4));
}

// K=256 GEMM: 32 edges (2 m-tiles) x 128 cols (8 n-tiles) per wave.
// A from swizzled LDS act (wave-private rows); B frag-linear in global,
// double-buffer staged to LDS, 1 barrier per K-chunk, chunk+2 reg prefetch.
__device__ __forceinline__ void gemm256(char* smem, const __bf16* wfmat,
                                        const float* bsrc, const float* sc_src,
                                        const float* be_src,
                                        int tid, int lane, int m0, int n0b,
                                        f32x4 acc[2][8]) {
  const uint4* wsrc = (const uint4*)wfmat;
  uint4 sa[2], sb[2];
  sa[0] = wsrc[tid];        sb[0] = wsrc[512 + tid];
  sa[1] = wsrc[1024 + tid]; sb[1] = wsrc[1536 + tid];
  uint4* buf0 = (uint4*)(smem + LDS_WSG);
  buf0[tid] = sa[0]; buf0[512 + tid] = sb[0];
  __syncthreads();  // chunk0 staged; all waves past previous phase's LDS reads
  float* bias = (float*)(smem + LDS_BIAS);
  if (tid < Hh) {
    bias[tid] = bsrc[tid];
    if (sc_src != nullptr) {
      ((float*)(smem + LDS_SC))[tid] = sc_src[tid] * BN_RS;
      ((float*)(smem + LDS_SBE))[tid] = be_src[tid];
    }
  }
  const int kgb = (lane >> 4) * 16;  // A k-group byte offset
#pragma unroll
  for (int kt = 0; kt < 8; ++kt) {
    const char* bbase = smem + LDS_WSG + (kt & 1) * 16384;
    const int r0 = m0 + (lane & 15), r1 = r0 + 16;
    bf16x8 af0 = *(const bf16x8*)(smem + LDS_ACT + r0 * 512 + ((kt * 64 + kgb) ^ ((r0 & 7) << 4)));
    bf16x8 af1 = *(const bf16x8*)(smem + LDS_ACT + r1 * 512 + ((kt * 64 + kgb) ^ ((r1 & 7) << 4)));
#pragma unroll
    for (int nt = 0; nt < 8; ++nt) {
      bf16x8 bfr = *(const bf16x8*)(bbase + ((n0b + nt) * 64 + lane) * 16);
      acc[0][nt] = MFMA16(af0, bfr, acc[0][nt]);
      acc[1][nt] = MFMA16(af1, bfr, acc[1][nt]);
    }
    if (kt < 7) {
      uint4* dst = (uint4*)(smem + LDS_WSG + ((kt + 1) & 1) * 16384);
      dst[tid] = sa[(kt + 1) & 1]; dst[512 + tid] = sb[(kt + 1) & 1];
      if (kt < 6) {
        sa[kt & 1] = wsrc[(kt + 2) * 1024 + tid];
        sb[kt & 1] = wsrc[(kt + 2) * 1024 + 512 + tid];
      }
    }
    __syncthreads();
  }
}

__global__ __launch_bounds__(512, 1)
void edge_kernel(const float* __restrict__ x, const float* __restrict__ rel_rec,
                 const float* __restrict__ rel_send, const float* __restrict__ rel_type,
                 const float* __restrict__ mf1_w, const float* __restrict__ mf1_b,
                 const float* __restrict__ mf2_b, const float* __restrict__ at1_b1,
                 const float* __restrict__ at1_b2, const float* __restrict__ at1_g,
                 const float* __restrict__ at1_be, const __bf16* __restrict__ wf,
                 const __bf16* __restrict__ rra, float* __restrict__ g_agg) {
  extern __shared__ char smem[];
  float* xs = (float*)(smem + LDS_XS);
  float* pm = (float*)(smem + LDS_PM);
  float* rt = (float*)(smem + LDS_RT);
  float* bias = (float*)(smem + LDS_BIAS);
  float* fb = (float*)(smem + LDS_FB);
  float* sc = (float*)(smem + LDS_SC);
  float* sbe = (float*)(smem + LDS_SBE);

  const int tid = threadIdx.x;
  const int lane = tid & 63;
  const int wv = tid >> 6;
  const int wvM = wv & 3, wvN = wv >> 2;
  const int m0 = wvM * 32, n0 = wvN * 128, n0b = wvN * 8;
  const int slice = blockIdx.x >> 2;
  const int split = blockIdx.x & 3;
  const int t_begin = (split < 2) ? split * 5 : 10 + (split - 2) * 4;
  const int t_cnt = (split < 2) ? 5 : 4;

  if (tid < Nn * 4) xs[tid] = x[slice * Nn * 4 + tid];

  // cross-tile register accumulator for agg GEMM
  f32x4 ag[3][2];
#pragma unroll
  for (int mt2 = 0; mt2 < 3; ++mt2)
#pragma unroll
    for (int ntl = 0; ntl < 2; ++ntl) ag[mt2][ntl] = (f32x4){0.f, 0.f, 0.f, 0.f};

  for (int tt = 0; tt < t_cnt; ++tt) {
    const int tile = t_begin + tt;
    const int e0 = tile * ETILE;
    const int ne = min(ETILE, Ee - e0);

    if (tid < ETILE * 2) {
      int e = tid >> 1, i = tid & 1;
      rt[tid] = (e < ne) ? rel_type[((size_t)slice * Ee + e0 + e) * 2 + i] : 0.f;
    }
    __syncthreads();  // xs (first tile) + rt visible

    // pre_msg k-major: pm[c][e], c: 0-3 senders, 4-7 receivers
#pragma unroll
    for (int p = 0; p < 2; ++p) {
      int t = p * 512 + tid;
      int c = t >> 7, e = t & 127;
      float s = 0.f;
      if (e < ne) {
        const float* rel = ((c < 4) ? rel_send : rel_rec) + (size_t)(e0 + e) * Nn;
        int f = c & 3;
#pragma unroll
        for (int n = 0; n < Nn; ++n) s += rel[n] * xs[n * 4 + f];
      }
      pm[c * 128 + e] = s;
    }

    f32x4 allm[2][8];
#pragma unroll
    for (int mt = 0; mt < 2; ++mt)
#pragma unroll
      for (int nt = 0; nt < 8; ++nt) allm[mt][nt] = (f32x4){0.f, 0.f, 0.f, 0.f};

    for (int ty = 0; ty < 2; ++ty) {
      // stage mf1[ty] into wsg buf1 (disjoint from gemm prologue's buf0) + fc1 bias
      ((uint4*)(smem + LDS_WSG + 16384))[tid] = ((const uint4*)(mf1_w + ty * 2048))[tid];
      if (tid < Hh) fb[tid] = mf1_b[ty * Hh + tid];
      __syncthreads();  // also covers pm writes
      // fc1 (K=8) -> act (bf16, swizzled)
      const float* wsf = (const float*)(smem + LDS_WSG + 16384);
#pragma unroll
      for (int it = 0; it < 8; ++it) {
        int t = it * 512 + tid;
        int e = t & 127, hc = t >> 7;
        float pmr[8];
#pragma unroll
        for (int k = 0; k < 8; ++k) pmr[k] = pm[k * 128 + e];
        bf16x8 pv;
#pragma unroll
        for (int j = 0; j < 8; ++j) {
          int h = hc * 8 + j;
          float s = fb[h];
#pragma unroll
          for (int k = 0; k < 8; ++k) s = fmaf(pmr[k], wsf[h * 8 + k], s);
          pv[j] = (__bf16)fmaxf(s, 0.f);
        }
        *(bf16x8*)(smem + LDS_ACT + aoff(e, hc * 16)) = pv;
      }
      f32x4 acc[2][8];
#pragma unroll
      for (int mt = 0; mt < 2; ++mt)
#pragma unroll
        for (int nt = 0; nt < 8; ++nt) acc[mt][nt] = (f32x4){0.f, 0.f, 0.f, 0.f};
      gemm256(smem, wf + (size_t)ty * 65536, mf2_b + ty * Hh, nullptr, nullptr,
              tid, lane, m0, n0b, acc);
#pragma unroll
      for (int mt = 0; mt < 2; ++mt) {
        float rtv[4];
#pragma unroll
        for (int r = 0; r < 4; ++r) rtv[r] = rt[(m0 + mt * 16 + (lane >> 4) * 4 + r) * 2 + ty];
#pragma unroll
        for (int nt = 0; nt < 8; ++nt) {
          float bb = bias[n0 + nt * 16 + (lane & 15)];
#pragma unroll
          for (int r = 0; r < 4; ++r)
            allm[mt][nt][r] += fmaxf(acc[mt][nt][r] + bb, 0.f) * rtv[r];
        }
      }
    }

    // all_msgs -> act in place (each wave writes its own rows x its own cols)
#pragma unroll
    for (int mt = 0; mt < 2; ++mt)
#pragma unroll
      for (int nt = 0; nt < 8; ++nt)
#pragma unroll
        for (int r = 0; r < 4; ++r) {
          int e = m0 + mt * 16 + (lane >> 4) * 4 + r;
          int cb = (n0 + nt * 16 + (lane & 15)) * 2;
          *(__bf16*)(smem + LDS_ACT + aoff(e, cb)) = (__bf16)allm[mt][nt][r];
        }

    // at1 layer 1: act -> elu -> act (in place)
    {
      f32x4 acc[2][8];
#pragma unroll
      for (int mt = 0; mt < 2; ++mt)
#pragma unroll
        for (int nt = 0; nt < 8; ++nt) acc[mt][nt] = (f32x4){0.f, 0.f, 0.f, 0.f};
      gemm256(smem, wf + (size_t)2 * 65536, at1_b1, nullptr, nullptr,
              tid, lane, m0, n0b, acc);
#pragma unroll
      for (int mt = 0; mt < 2; ++mt)
#pragma unroll
        for (int nt = 0; nt < 8; ++nt) {
          float bb = bias[n0 + nt * 16 + (lane & 15)];
#pragma unroll
          for (int r = 0; r < 4; ++r) {
            int e = m0 + mt * 16 + (lane >> 4) * 4 + r;
            int cb = (n0 + nt * 16 + (lane & 15)) * 2;
            *(__bf16*)(smem + LDS_ACT + aoff(e, cb)) = (__bf16)eluf(acc[mt][nt][r] + bb);
          }
        }
    }

    // at1 layer 2: act -> elu*sc+be -> agg B-frags (overwrites act region)
    {
      f32x4 acc[2][8];
#pragma unroll
      for (int mt = 0; mt < 2; ++mt)
#pragma unroll
        for (int nt = 0; nt < 8; ++nt) acc[mt][nt] = (f32x4){0.f, 0.f, 0.f, 0.f};
      gemm256(smem, wf + (size_t)3 * 65536, at1_b2, at1_g, at1_be,
              tid, lane, m0, n0b, acc);
      // after final kt sync all act reads are done -> safe to overwrite with B-frags
      const int j0 = ((lane >> 4) & 1) * 4;
      const int lh_base = (lane >> 4) >> 1;
#pragma unroll
      for (int mt = 0; mt < 2; ++mt) {
        const int lane_hi = mt * 2 + lh_base;
#pragma unroll
        for (int nt = 0; nt < 8; ++nt) {
          int col = n0 + nt * 16 + (lane & 15);
          float bb = bias[col], s1 = sc[col], s2 = sbe[col];
          bf16x4 pk;
#pragma unroll
          for (int r = 0; r < 4; ++r)
            pk[r] = (__bf16)(eluf(acc[mt][nt][r] + bb) * s1 + s2);
          int addr = ((((wvM * 16) + (n0b + nt)) * 64 + lane_hi * 16 + (lane & 15)) * 8 + j0) * 2;
          *(bf16x4*)(smem + LDS_ACT + addr) = pk;
        }
      }
    }
    __syncthreads();  // B-frags visible

    // aggregation GEMM: ag += rel_rec[tile]^T @ h_edges  (M=48, N=256, K=128)
    const bf16x8* rraw = (const bf16x8*)rra + (size_t)tile * 768;
#pragma unroll
    for (int kt2 = 0; kt2 < 4; ++kt2) {
      bf16x8 b0 = *(const bf16x8*)(smem + LDS_ACT + ((kt2 * 16 + wv * 2 + 0) * 64 + lane) * 16);
      bf16x8 b1 = *(const bf16x8*)(smem + LDS_ACT + ((kt2 * 16 + wv * 2 + 1) * 64 + lane) * 16);
#pragma unroll
      for (int mt2 = 0; mt2 < 3; ++mt2) {
        bf16x8 a = rraw[(kt2 * 3 + mt2) * 64 + lane];
        ag[mt2][0] = MFMA16(a, b0, ag[mt2][0]);
        ag[mt2][1] = MFMA16(a, b1, ag[mt2][1]);
      }
    }
    __syncthreads();  // agg reads of ACT done before next tile's fc1 overwrites
  }

  // one atomic pass per block (4 blocks contribute per slice)
  float* dst = g_agg + (size_t)slice * Nn * Hh;
#pragma unroll
  for (int mt2 = 0; mt2 < 3; ++mt2)
#pragma unroll
    for (int ntl = 0; ntl < 2; ++ntl) {
      int h = (wv * 2 + ntl) * 16 + (lane & 15);
#pragma unroll
      for (int r = 0; r < 4; ++r) {
        int n = mt2 * 16 + (lane >> 4) * 4 + r;
        atomicAdd(dst + n * Hh + h, ag[mt2][ntl][r]);
      }
    }
}

// 4 weight matrices [256][256] fp32 -> bf16 MFMA B-fragment-linear
__global__ void prep_frag(const float* __restrict__ mf2_w, const float* __restrict__ at1_w1,
                          const float* __restrict__ at1_w2, __bf16* __restrict__ wfdst) {
  int id = blockIdx.x * 256 + threadIdx.x;  // 32768 total
  int mat = id >> 13, r = id & 8191;
  int kt = r >> 10, q = r & 1023, nt = q >> 6, l = q & 63;
  int row = nt * 16 + (l & 15), col = kt * 32 + (l >> 4) * 8;
  const float* src = (mat == 0) ? mf2_w : (mat == 1) ? (mf2_w + 65536)
                   : (mat == 2) ? at1_w1 : at1_w2;
  const float* p = src + row * 256 + col;
  __bf16* d = wfdst + (size_t)mat * 65536 + ((size_t)(kt * 16 + nt) * 64 + l) * 8;
#pragma unroll
  for (int j = 0; j < 8; ++j) d[j] = (__bf16)p[j];
}

// rel_rec^T per-tile bf16 A-fragments: rra[tile][kt2][mt2][lane][8]
__global__ void prep_rra(const float* __restrict__ rel_rec, __bf16* __restrict__ rra) {
  int id = blockIdx.x * 256 + threadIdx.x;  // 54*256 = 13824
  int tile = id / 768, r = id % 768;
  int kt2 = r / 192, r2 = r % 192, mt2 = r2 >> 6, l = r2 & 63;
  int ebase = tile * 128 + kt2 * 32 + (l >> 4) * 8;
  int n = mt2 * 16 + (l & 15);
  bf16x8 v;
#pragma unroll
  for (int j = 0; j < 8; ++j) {
    int e = ebase + j;
    v[j] = (__bf16)((e < Ee) ? rel_rec[(size_t)e * Nn + n] : 0.f);
  }
  ((bf16x8*)rra)[id] = v;
}

// transpose node-side weights (fp32) for coalesced lane reads
__global__ void prep_node(const float* __restrict__ at5_w1, const float* __restrict__ at5_w2,
                          const float* __restrict__ o1_w, const float* __restrict__ o2_w,
                          const float* __restrict__ o3_w, float* __restrict__ ws) {
  int id = blockIdx.x * 256 + threadIdx.x;
  float* T1 = ws;
  float* T2 = T1 + 67600;
  float* To1 = T2 + 67600;
  float* To2 = To1 + 66560;
  float* To3 = To2 + 65536;
  if (id < 67600) { int o = id % 260, k = id / 260; T1[k * 260 + o] = at5_w1[o * 260 + k]; return; }
  id -= 67600;
  if (id < 67600) { int o = id % 260, k = id / 260; T2[k * 260 + o] = at5_w2[o * 260 + k]; return; }
  id -= 67600;
  if (id < 66560) { int o = id & 255, k = id >> 8; To1[k * 256 + o] = o1_w[o * 260 + k]; return; }
  id -= 66560;
  if (id < 65536) { int o = id & 255, k = id >> 8; To2[k * 256 + o] = o2_w[o * 256 + k]; return; }
  id -= 65536;
  if (id < 1024) { int f = id & 3, k = id >> 2; To3[k * 4 + f] = o3_w[f * 256 + k]; }
}

__global__ __launch_bounds__(256, 4)
void node_kernel(const float* __restrict__ g_agg, const float* __restrict__ x,
                 const float* __restrict__ T1, const float* __restrict__ T2,
                 const float* __restrict__ To1, const float* __restrict__ To2,
                 const float* __restrict__ To3, const float* __restrict__ at5_b1,
                 const float* __restrict__ at5_b2, const float* __restrict__ at5_g,
                 const float* __restrict__ at5_be, const float* __restrict__ o1_b,
                 const float* __restrict__ o2_b, const float* __restrict__ o3_b,
                 float* __restrict__ out) {
  __shared__ float bufA[12 * 264], bufB[12 * 264], xres[12 * 4];
  const int tid = threadIdx.x;
  const int slice = blockIdx.x >> 2, rg = blockIdx.x & 3;
  const int n0 = rg * 12;
  for (int t = tid; t < 12 * 256; t += 256) {
    int r = t >> 8, h = t & 255;
    bufA[r * 264 + h] = g_agg[(size_t)slice * 12288 + (size_t)(n0 + r) * 256 + h];
  }
  if (tid < 48) {
    int r = tid >> 2, f = tid & 3;
    float v = x[(size_t)slice * 192 + (n0 + r) * 4 + f];
    bufA[r * 264 + 256 + f] = v;
    xres[tid] = v;
  }
  __syncthreads();

  auto layer = [&](const float* WT, const float* bsrc, const float* in, float* outb,
                   int K, int O, int act, const float* gsc, const float* gbe) {
    for (int o = tid; o < O; o += 256) {
      float a[12];
      float bb = bsrc[o];
#pragma unroll
      for (int r = 0; r < 12; ++r) a[r] = bb;
      for (int k = 0; k < K; ++k) {
        float w = WT[k * O + o];
#pragma unroll
        for (int r = 0; r < 12; ++r) a[r] = fmaf(in[r * 264 + k], w, a[r]);
      }
      float scv = 1.f, bev = 0.f;
      if (act == 2) { scv = gsc[o] * BN_RS; bev = gbe[o]; }
#pragma unroll
      for (int r = 0; r < 12; ++r) {
        float v = a[r];
        v = (act == 0) ? fmaxf(v, 0.f) : eluf(v);
        if (act == 2) v = v * scv + bev;
        outb[r * 264 + o] = v;
      }
    }
    __syncthreads();
  };

  layer(T1, at5_b1, bufA, bufB, 260, 260, 1, nullptr, nullptr);
  layer(T2, at5_b2, bufB, bufA, 260, 260, 2, at5_g, at5_be);
  layer(To1, o1_b, bufA, bufB, 260, 256, 0, nullptr, nullptr);
  layer(To2, o2_b, bufB, bufA, 256, 256, 0, nullptr, nullptr);
  if (tid < 48) {
    int r = tid >> 2, f = tid & 3;
    float s = o3_b[f];
    for (int k = 0; k < 256; ++k) s = fmaf(bufA[r * 264 + k], To3[k * 4 + f], s);
    out[(size_t)slice * 192 + (n0 + r) * 4 + f] = xres[tid] + s;
  }
}

extern "C" void kernel_launch(void* const* d_in, const int* in_sizes, int n_in,
                              void* d_out, int out_size, void* d_ws, size_t ws_size,
                              hipStream_t stream) {
  const float* x = (const float*)d_in[0];
  const float* rel_rec = (const float*)d_in[1];
  const float* rel_send = (const float*)d_in[2];
  const float* rel_type = (const float*)d_in[3];
  const float* mf1_w = (const float*)d_in[4];
  const float* mf1_b = (const float*)d_in[5];
  const float* mf2_w = (const float*)d_in[6];
  const float* mf2_b = (const float*)d_in[7];
  const float* at1_w1 = (const float*)d_in[8];
  const float* at1_b1 = (const float*)d_in[9];
  const float* at1_w2 = (const float*)d_in[10];
  const float* at1_b2 = (const float*)d_in[11];
  const float* at1_g = (const float*)d_in[12];
  const float* at1_be = (const float*)d_in[13];
  const float* at5_w1 = (const float*)d_in[14];
  const float* at5_b1 = (const float*)d_in[15];
  const float* at5_w2 = (const float*)d_in[16];
  const float* at5_b2 = (const float*)d_in[17];
  const float* at5_g = (const float*)d_in[18];
  const float* at5_be = (const float*)d_in[19];
  const float* o1_w = (const float*)d_in[20];
  const float* o1_b = (const float*)d_in[21];
  const float* o2_w = (const float*)d_in[22];
  const float* o2_b = (const float*)d_in[23];
  const float* o3_w = (const float*)d_in[24];
  const float* o3_b = (const float*)d_in[25];

  char* ws = (char*)d_ws;
  __bf16* wf = (__bf16*)(ws + WS_WF);
  __bf16* rra = (__bf16*)(ws + WS_RRA);
  float* tnode = (float*)(ws + WS_TN);
  float* g_agg = (float*)(ws + WS_AGG);

  hipMemsetAsync(g_agg, 0, (size_t)BT * Nn * Hh * 4, stream);
  prep_frag<<<128, 256, 0, stream>>>(mf2_w, at1_w1, at1_w2, wf);
  prep_rra<<<54, 256, 0, stream>>>(rel_rec, rra);
  prep_node<<<1049, 256, 0, stream>>>(at5_w1, at5_w2, o1_w, o2_w, o3_w, tnode);

  hipFuncSetAttribute((const void*)edge_kernel,
                      hipFuncAttributeMaxDynamicSharedMemorySize, LDS_EDGE_BYTES);
  edge_kernel<<<BT * 4, 512, LDS_EDGE_BYTES, stream>>>(
      x, rel_rec, rel_send, rel_type, mf1_w, mf1_b, mf2_b, at1_b1, at1_b2,
      at1_g, at1_be, wf, rra, g_agg);

  node_kernel<<<256, 256, 0, stream>>>(g_agg, x, tnode, tnode + 67600,
                                       tnode + 135200, tnode + 201760, tnode + 267296,
                                       at5_b1, at5_b2, at5_g, at5_be,
                                       o1_b, o2_b, o3_b, (float*)d_out);
}

// Round 5
// 656.203 us; speedup vs baseline: 1.1577x; 1.1570x over previous
//
#include <hip/hip_runtime.h>
#include <hip/hip_bf16.h>
#include <math.h>

typedef __bf16 bf16x8 __attribute__((ext_vector_type(8)));
typedef __bf16 bf16x4 __attribute__((ext_vector_type(4)));
typedef float f32x4 __attribute__((ext_vector_type(4)));

#define MFMA16(a,b,c) __builtin_amdgcn_mfma_f32_16x16x32_bf16(a,b,c,0,0,0)

static constexpr int Nn = 48, Hh = 256;
static constexpr int Ee = 2256, BT = 64;
static constexpr int ETILE = 128, NTILES = 18;         // 18*128 = 2304 >= 2256
static constexpr float BN_RS = 0.9999950000374998f;     // 1/sqrt(1+1e-5)

// ---- ws layout (bytes), total ~5.0 MB ----
static constexpr size_t WS_WF  = 0;        // 4 mats bf16 frag-linear: 524288
static constexpr size_t WS_RRA = 524288;   // rel_rec^T A-frags: 221184
static constexpr size_t WS_TN  = 745472;   // node transposed weights
static constexpr size_t WS_AGG = 1818752;  // g_agg [64][48][256] f32 = 3145728

// ---- LDS layout (bytes) ----
static constexpr int LDS_ACT  = 0;        // [128][512B] bf16 act, swizzled; reused as agg B-frags
static constexpr int LDS_WSG  = 65536;    // 2 x 16384 double-buffered weight chunk (DMA dest)
static constexpr int LDS_MF1  = 98304;    // 8192 (mf1 weights, DMA dest)
static constexpr int LDS_XS   = 106496;   // 192 f32
static constexpr int LDS_PM   = 107264;   // pm[8][128] f32
static constexpr int LDS_RT   = 111360;   // [128][2] f32
static constexpr int LDS_BIAS = 112384;   // 256 f32
static constexpr int LDS_FB   = 113408;   // 256 f32 (fc1 bias)
static constexpr int LDS_SC   = 114432;   // 256 f32
static constexpr int LDS_SBE  = 115456;   // 256 f32
static constexpr int LDS_EDGE_BYTES = 116480;

__device__ __forceinline__ float eluf(float v) { return v > 0.f ? v : __expf(v) - 1.f; }

// async global->LDS, 16B per lane; lds dest must be wave-uniform base (HW adds lane*16)
typedef __attribute__((address_space(1))) const unsigned int as1_uint;
typedef __attribute__((address_space(3))) unsigned int as3_uint;
__device__ __forceinline__ void gload16(const void* g, void* l) {
  __builtin_amdgcn_global_load_lds((as1_uint*)g, (as3_uint*)l, 16, 0, 0);
}

// row-swizzled byte offset inside the [128][512B] activation buffer
__device__ __forceinline__ int aoff(int e, int colbyte) {
  return e * 512 + (colbyte ^ ((e & 7) << 4));
}

// K=256 GEMM: 64 edges (4 m-tiles) x 64 cols (4 n-tiles) per wave.
// A from swizzled LDS act; B frag-linear in global, DMA-staged per-32-K chunk
// (double-buffered, 1 barrier per chunk, loads fly during MFMA).
__device__ __forceinline__ void gemm256(char* smem, const __bf16* wfmat,
                                        const float* bsrc, const float* sc_src,
                                        const float* be_src,
                                        int tid, int lane, int wv, int m0, int n0b,
                                        f32x4 acc[4][4]) {
  const char* wsrcb = (const char*)wfmat;
  char* wsg = smem + LDS_WSG;
  const int goff = wv * 2048 + lane * 16;
  // stage chunk 0 into buf0
  gload16(wsrcb + goff, wsg + wv * 2048);
  gload16(wsrcb + goff + 1024, wsg + wv * 2048 + 1024);
  if (tid < Hh) {
    ((float*)(smem + LDS_BIAS))[tid] = bsrc[tid];
    if (sc_src != nullptr) {
      ((float*)(smem + LDS_SC))[tid] = sc_src[tid] * BN_RS;
      ((float*)(smem + LDS_SBE))[tid] = be_src[tid];
    }
  }
  __syncthreads();  // chunk0 landed (vmcnt drain) + bias visible
  const int kgb = (lane >> 4) * 16;  // A k-group byte offset
#pragma unroll
  for (int kt = 0; kt < 8; ++kt) {
    const char* bb = wsg + (kt & 1) * 16384;
    if (kt < 7) {  // issue next chunk DMA; flies during this chunk's MFMA
      char* nb = wsg + ((kt + 1) & 1) * 16384 + wv * 2048;
      gload16(wsrcb + (kt + 1) * 16384 + goff, nb);
      gload16(wsrcb + (kt + 1) * 16384 + goff + 1024, nb + 1024);
    }
    bf16x8 af[4];
#pragma unroll
    for (int mt = 0; mt < 4; ++mt) {
      int r = m0 + mt * 16 + (lane & 15);
      af[mt] = *(const bf16x8*)(smem + LDS_ACT + r * 512 + ((kt * 64 + kgb) ^ ((r & 7) << 4)));
    }
#pragma unroll
    for (int nt = 0; nt < 4; ++nt) {
      bf16x8 bfr = *(const bf16x8*)(bb + ((n0b + nt) * 64 + lane) * 16);
#pragma unroll
      for (int mt = 0; mt < 4; ++mt)
        acc[mt][nt] = MFMA16(af[mt], bfr, acc[mt][nt]);
    }
    __syncthreads();  // next chunk landed; buf safe to overwrite
  }
}

__global__ __launch_bounds__(512)
__attribute__((amdgpu_waves_per_eu(2, 2)))
void edge_kernel(const float* __restrict__ x, const float* __restrict__ rel_rec,
                 const float* __restrict__ rel_send, const float* __restrict__ rel_type,
                 const float* __restrict__ mf1_w, const float* __restrict__ mf1_b,
                 const float* __restrict__ mf2_b, const float* __restrict__ at1_b1,
                 const float* __restrict__ at1_b2, const float* __restrict__ at1_g,
                 const float* __restrict__ at1_be, const __bf16* __restrict__ wf,
                 const __bf16* __restrict__ rra, float* __restrict__ g_agg) {
  extern __shared__ char smem[];
  float* xs = (float*)(smem + LDS_XS);
  float* pm = (float*)(smem + LDS_PM);
  float* rt = (float*)(smem + LDS_RT);
  float* bias = (float*)(smem + LDS_BIAS);
  float* fb = (float*)(smem + LDS_FB);
  float* sc = (float*)(smem + LDS_SC);
  float* sbe = (float*)(smem + LDS_SBE);

  const int tid = threadIdx.x;
  const int lane = tid & 63;
  const int wv = tid >> 6;
  const int lg = lane >> 4;
  const int wvM = wv & 1, wvN = wv >> 1;
  const int m0 = wvM * 64, n0 = wvN * 64, n0b = wvN * 4;
  const int slice = blockIdx.x >> 2;
  const int split = blockIdx.x & 3;
  const int t_begin = (split < 2) ? split * 5 : 10 + (split - 2) * 4;
  const int t_cnt = (split < 2) ? 5 : 4;

  if (tid < Nn * 4) xs[tid] = x[slice * Nn * 4 + tid];

  // cross-tile register accumulator for agg GEMM
  f32x4 ag[3][2];
#pragma unroll
  for (int mt2 = 0; mt2 < 3; ++mt2)
#pragma unroll
    for (int ntl = 0; ntl < 2; ++ntl) ag[mt2][ntl] = (f32x4){0.f, 0.f, 0.f, 0.f};

  for (int tt = 0; tt < t_cnt; ++tt) {
    const int tile = t_begin + tt;
    const int e0 = tile * ETILE;
    const int ne = min(ETILE, Ee - e0);

    if (tid < ETILE * 2) {
      int e = tid >> 1, i = tid & 1;
      rt[tid] = (e < ne) ? rel_type[((size_t)slice * Ee + e0 + e) * 2 + i] : 0.f;
    }
    __syncthreads();  // xs (first tile) + rt visible

    // pre_msg k-major: pm[c][e], c: 0-3 senders, 4-7 receivers
#pragma unroll
    for (int p = 0; p < 2; ++p) {
      int t = p * 512 + tid;
      int c = t >> 7, e = t & 127;
      float s = 0.f;
      if (e < ne) {
        const float* rel = ((c < 4) ? rel_send : rel_rec) + (size_t)(e0 + e) * Nn;
        int f = c & 3;
#pragma unroll
        for (int n = 0; n < Nn; ++n) s += rel[n] * xs[n * 4 + f];
      }
      pm[c * 128 + e] = s;
    }

    f32x4 allm[4][4];
#pragma unroll
    for (int mt = 0; mt < 4; ++mt)
#pragma unroll
      for (int nt = 0; nt < 4; ++nt) allm[mt][nt] = (f32x4){0.f, 0.f, 0.f, 0.f};

    for (int ty = 0; ty < 2; ++ty) {
      // stage mf1[ty] (8 KB) into LDS_MF1 via DMA + fc1 bias
      gload16((const char*)(mf1_w + ty * 2048) + wv * 1024 + lane * 16,
              smem + LDS_MF1 + wv * 1024);
      if (tid < Hh) fb[tid] = mf1_b[ty * Hh + tid];
      __syncthreads();  // pm + mf1 + fb visible
      // fc1 (K=8) -> act (bf16, swizzled)
      const float* wsf = (const float*)(smem + LDS_MF1);
#pragma unroll
      for (int it = 0; it < 8; ++it) {
        int t = it * 512 + tid;
        int e = t & 127, hc = t >> 7;
        float pmr[8];
#pragma unroll
        for (int k = 0; k < 8; ++k) pmr[k] = pm[k * 128 + e];
        bf16x8 pv;
#pragma unroll
        for (int j = 0; j < 8; ++j) {
          int h = hc * 8 + j;
          float s = fb[h];
#pragma unroll
          for (int k = 0; k < 8; ++k) s = fmaf(pmr[k], wsf[h * 8 + k], s);
          pv[j] = (__bf16)fmaxf(s, 0.f);
        }
        *(bf16x8*)(smem + LDS_ACT + aoff(e, hc * 16)) = pv;
      }
      f32x4 acc[4][4];
#pragma unroll
      for (int mt = 0; mt < 4; ++mt)
#pragma unroll
        for (int nt = 0; nt < 4; ++nt) acc[mt][nt] = (f32x4){0.f, 0.f, 0.f, 0.f};
      gemm256(smem, wf + (size_t)ty * 65536, mf2_b + ty * Hh, nullptr, nullptr,
              tid, lane, wv, m0, n0b, acc);
#pragma unroll
      for (int mt = 0; mt < 4; ++mt) {
        float rtv[4];
#pragma unroll
        for (int r = 0; r < 4; ++r) rtv[r] = rt[(m0 + mt * 16 + lg * 4 + r) * 2 + ty];
#pragma unroll
        for (int nt = 0; nt < 4; ++nt) {
          float bb = bias[n0 + nt * 16 + (lane & 15)];
#pragma unroll
          for (int r = 0; r < 4; ++r)
            allm[mt][nt][r] += fmaxf(acc[mt][nt][r] + bb, 0.f) * rtv[r];
        }
      }
    }

    // all_msgs -> act in place (each wave writes its own rows x its own cols)
#pragma unroll
    for (int mt = 0; mt < 4; ++mt)
#pragma unroll
      for (int nt = 0; nt < 4; ++nt)
#pragma unroll
        for (int r = 0; r < 4; ++r) {
          int e = m0 + mt * 16 + lg * 4 + r;
          int cb = (n0 + nt * 16 + (lane & 15)) * 2;
          *(__bf16*)(smem + LDS_ACT + aoff(e, cb)) = (__bf16)allm[mt][nt][r];
        }

    // at1 layer 1: act -> elu -> act (in place)
    {
      f32x4 acc[4][4];
#pragma unroll
      for (int mt = 0; mt < 4; ++mt)
#pragma unroll
        for (int nt = 0; nt < 4; ++nt) acc[mt][nt] = (f32x4){0.f, 0.f, 0.f, 0.f};
      gemm256(smem, wf + (size_t)2 * 65536, at1_b1, nullptr, nullptr,
              tid, lane, wv, m0, n0b, acc);
#pragma unroll
      for (int mt = 0; mt < 4; ++mt)
#pragma unroll
        for (int nt = 0; nt < 4; ++nt) {
          float bb = bias[n0 + nt * 16 + (lane & 15)];
#pragma unroll
          for (int r = 0; r < 4; ++r) {
            int e = m0 + mt * 16 + lg * 4 + r;
            int cb = (n0 + nt * 16 + (lane & 15)) * 2;
            *(__bf16*)(smem + LDS_ACT + aoff(e, cb)) = (__bf16)eluf(acc[mt][nt][r] + bb);
          }
        }
    }

    // at1 layer 2: act -> elu*sc+be -> agg B-frags (overwrites act region)
    {
      f32x4 acc[4][4];
#pragma unroll
      for (int mt = 0; mt < 4; ++mt)
#pragma unroll
        for (int nt = 0; nt < 4; ++nt) acc[mt][nt] = (f32x4){0.f, 0.f, 0.f, 0.f};
      gemm256(smem, wf + (size_t)3 * 65536, at1_b2, at1_g, at1_be,
              tid, lane, wv, m0, n0b, acc);
      // after final kt sync all act reads done -> safe to overwrite with B-frags.
      // element (e=edge, col): ktile=e>>5, kin=e&31, lane'=(col&15)|((kin>>3)<<4), j=kin&7
      const int j0 = (lg & 1) * 4;
#pragma unroll
      for (int mt = 0; mt < 4; ++mt) {
        const int ktile = wvM * 2 + (mt >> 1);
        const int lane2 = (lane & 15) | (((mt & 1) * 2 + (lg >> 1)) << 4);
#pragma unroll
        for (int nt = 0; nt < 4; ++nt) {
          int col = n0 + nt * 16 + (lane & 15);
          float bb = bias[col], s1 = sc[col], s2 = sbe[col];
          bf16x4 pk;
#pragma unroll
          for (int r = 0; r < 4; ++r)
            pk[r] = (__bf16)(eluf(acc[mt][nt][r] + bb) * s1 + s2);
          int addr = (((ktile * 16 + n0b + nt) * 64 + lane2) * 8 + j0) * 2;
          *(bf16x4*)(smem + LDS_ACT + addr) = pk;
        }
      }
    }
    __syncthreads();  // B-frags visible

    // aggregation GEMM: ag += rel_rec[tile]^T @ h_edges  (M=48, N=256, K=128)
    const bf16x8* rraw = (const bf16x8*)rra + (size_t)tile * 768;
#pragma unroll
    for (int kt2 = 0; kt2 < 4; ++kt2) {
      bf16x8 b0 = *(const bf16x8*)(smem + LDS_ACT + ((kt2 * 16 + wv * 2 + 0) * 64 + lane) * 16);
      bf16x8 b1 = *(const bf16x8*)(smem + LDS_ACT + ((kt2 * 16 + wv * 2 + 1) * 64 + lane) * 16);
#pragma unroll
      for (int mt2 = 0; mt2 < 3; ++mt2) {
        bf16x8 a = rraw[(kt2 * 3 + mt2) * 64 + lane];
        ag[mt2][0] = MFMA16(a, b0, ag[mt2][0]);
        ag[mt2][1] = MFMA16(a, b1, ag[mt2][1]);
      }
    }
    __syncthreads();  // agg reads of ACT done before next tile's fc1 overwrites
  }

  // one atomic pass per block (4 blocks contribute per slice)
  float* dst = g_agg + (size_t)slice * Nn * Hh;
#pragma unroll
  for (int mt2 = 0; mt2 < 3; ++mt2)
#pragma unroll
    for (int ntl = 0; ntl < 2; ++ntl) {
      int h = (wv * 2 + ntl) * 16 + (lane & 15);
#pragma unroll
      for (int r = 0; r < 4; ++r) {
        int n = mt2 * 16 + lg * 4 + r;
        atomicAdd(dst + n * Hh + h, ag[mt2][ntl][r]);
      }
    }
}

// 4 weight matrices [256][256] fp32 -> bf16 MFMA B-fragment-linear
__global__ void prep_frag(const float* __restrict__ mf2_w, const float* __restrict__ at1_w1,
                          const float* __restrict__ at1_w2, __bf16* __restrict__ wfdst) {
  int id = blockIdx.x * 256 + threadIdx.x;  // 32768 total
  int mat = id >> 13, r = id & 8191;
  int kt = r >> 10, q = r & 1023, nt = q >> 6, l = q & 63;
  int row = nt * 16 + (l & 15), col = kt * 32 + (l >> 4) * 8;
  const float* src = (mat == 0) ? mf2_w : (mat == 1) ? (mf2_w + 65536)
                   : (mat == 2) ? at1_w1 : at1_w2;
  const float* p = src + row * 256 + col;
  __bf16* d = wfdst + (size_t)mat * 65536 + ((size_t)(kt * 16 + nt) * 64 + l) * 8;
#pragma unroll
  for (int j = 0; j < 8; ++j) d[j] = (__bf16)p[j];
}

// rel_rec^T per-tile bf16 A-fragments: rra[tile][kt2][mt2][lane][8]
__global__ void prep_rra(const float* __restrict__ rel_rec, __bf16* __restrict__ rra) {
  int id = blockIdx.x * 256 + threadIdx.x;  // 54*256 = 13824
  int tile = id / 768, r = id % 768;
  int kt2 = r / 192, r2 = r % 192, mt2 = r2 >> 6, l = r2 & 63;
  int ebase = tile * 128 + kt2 * 32 + (l >> 4) * 8;
  int n = mt2 * 16 + (l & 15);
  bf16x8 v;
#pragma unroll
  for (int j = 0; j < 8; ++j) {
    int e = ebase + j;
    v[j] = (__bf16)((e < Ee) ? rel_rec[(size_t)e * Nn + n] : 0.f);
  }
  ((bf16x8*)rra)[id] = v;
}

// transpose node-side weights (fp32) for coalesced lane reads
__global__ void prep_node(const float* __restrict__ at5_w1, const float* __restrict__ at5_w2,
                          const float* __restrict__ o1_w, const float* __restrict__ o2_w,
                          const float* __restrict__ o3_w, float* __restrict__ ws) {
  int id = blockIdx.x * 256 + threadIdx.x;
  float* T1 = ws;
  float* T2 = T1 + 67600;
  float* To1 = T2 + 67600;
  float* To2 = To1 + 66560;
  float* To3 = To2 + 65536;
  if (id < 67600) { int o = id % 260, k = id / 260; T1[k * 260 + o] = at5_w1[o * 260 + k]; return; }
  id -= 67600;
  if (id < 67600) { int o = id % 260, k = id / 260; T2[k * 260 + o] = at5_w2[o * 260 + k]; return; }
  id -= 67600;
  if (id < 66560) { int o = id & 255, k = id >> 8; To1[k * 256 + o] = o1_w[o * 260 + k]; return; }
  id -= 66560;
  if (id < 65536) { int o = id & 255, k = id >> 8; To2[k * 256 + o] = o2_w[o * 256 + k]; return; }
  id -= 65536;
  if (id < 1024) { int f = id & 3, k = id >> 2; To3[k * 4 + f] = o3_w[f * 256 + k]; }
}

__global__ __launch_bounds__(256, 4)
void node_kernel(const float* __restrict__ g_agg, const float* __restrict__ x,
                 const float* __restrict__ T1, const float* __restrict__ T2,
                 const float* __restrict__ To1, const float* __restrict__ To2,
                 const float* __restrict__ To3, const float* __restrict__ at5_b1,
                 const float* __restrict__ at5_b2, const float* __restrict__ at5_g,
                 const float* __restrict__ at5_be, const float* __restrict__ o1_b,
                 const float* __restrict__ o2_b, const float* __restrict__ o3_b,
                 float* __restrict__ out) {
  __shared__ float bufA[12 * 264], bufB[12 * 264], xres[12 * 4];
  const int tid = threadIdx.x;
  const int slice = blockIdx.x >> 2, rg = blockIdx.x & 3;
  const int n0 = rg * 12;
  for (int t = tid; t < 12 * 256; t += 256) {
    int r = t >> 8, h = t & 255;
    bufA[r * 264 + h] = g_agg[(size_t)slice * 12288 + (size_t)(n0 + r) * 256 + h];
  }
  if (tid < 48) {
    int r = tid >> 2, f = tid & 3;
    float v = x[(size_t)slice * 192 + (n0 + r) * 4 + f];
    bufA[r * 264 + 256 + f] = v;
    xres[tid] = v;
  }
  __syncthreads();

  auto layer = [&](const float* WT, const float* bsrc, const float* in, float* outb,
                   int K, int O, int act, const float* gsc, const float* gbe) {
    for (int o = tid; o < O; o += 256) {
      float a[12];
      float bb = bsrc[o];
#pragma unroll
      for (int r = 0; r < 12; ++r) a[r] = bb;
      for (int k = 0; k < K; ++k) {
        float w = WT[k * O + o];
#pragma unroll
        for (int r = 0; r < 12; ++r) a[r] = fmaf(in[r * 264 + k], w, a[r]);
      }
      float scv = 1.f, bev = 0.f;
      if (act == 2) { scv = gsc[o] * BN_RS; bev = gbe[o]; }
#pragma unroll
      for (int r = 0; r < 12; ++r) {
        float v = a[r];
        v = (act == 0) ? fmaxf(v, 0.f) : eluf(v);
        if (act == 2) v = v * scv + bev;
        outb[r * 264 + o] = v;
      }
    }
    __syncthreads();
  };

  layer(T1, at5_b1, bufA, bufB, 260, 260, 1, nullptr, nullptr);
  layer(T2, at5_b2, bufB, bufA, 260, 260, 2, at5_g, at5_be);
  layer(To1, o1_b, bufA, bufB, 260, 256, 0, nullptr, nullptr);
  layer(To2, o2_b, bufB, bufA, 256, 256, 0, nullptr, nullptr);
  if (tid < 48) {
    int r = tid >> 2, f = tid & 3;
    float s = o3_b[f];
    for (int k = 0; k < 256; ++k) s = fmaf(bufA[r * 264 + k], To3[k * 4 + f], s);
    out[(size_t)slice * 192 + (n0 + r) * 4 + f] = xres[tid] + s;
  }
}

extern "C" void kernel_launch(void* const* d_in, const int* in_sizes, int n_in,
                              void* d_out, int out_size, void* d_ws, size_t ws_size,
                              hipStream_t stream) {
  const float* x = (const float*)d_in[0];
  const float* rel_rec = (const float*)d_in[1];
  const float* rel_send = (const float*)d_in[2];
  const float* rel_type = (const float*)d_in[3];
  const float* mf1_w = (const float*)d_in[4];
  const float* mf1_b = (const float*)d_in[5];
  const float* mf2_w = (const float*)d_in[6];
  const float* mf2_b = (const float*)d_in[7];
  const float* at1_w1 = (const float*)d_in[8];
  const float* at1_b1 = (const float*)d_in[9];
  const float* at1_w2 = (const float*)d_in[10];
  const float* at1_b2 = (const float*)d_in[11];
  const float* at1_g = (const float*)d_in[12];
  const float* at1_be = (const float*)d_in[13];
  const float* at5_w1 = (const float*)d_in[14];
  const float* at5_b1 = (const float*)d_in[15];
  const float* at5_w2 = (const float*)d_in[16];
  const float* at5_b2 = (const float*)d_in[17];
  const float* at5_g = (const float*)d_in[18];
  const float* at5_be = (const float*)d_in[19];
  const float* o1_w = (const float*)d_in[20];
  const float* o1_b = (const float*)d_in[21];
  const float* o2_w = (const float*)d_in[22];
  const float* o2_b = (const float*)d_in[23];
  const float* o3_w = (const float*)d_in[24];
  const float* o3_b = (const float*)d_in[25];

  char* ws = (char*)d_ws;
  __bf16* wf = (__bf16*)(ws + WS_WF);
  __bf16* rra = (__bf16*)(ws + WS_RRA);
  float* tnode = (float*)(ws + WS_TN);
  float* g_agg = (float*)(ws + WS_AGG);

  hipMemsetAsync(g_agg, 0, (size_t)BT * Nn * Hh * 4, stream);
  prep_frag<<<128, 256, 0, stream>>>(mf2_w, at1_w1, at1_w2, wf);
  prep_rra<<<54, 256, 0, stream>>>(rel_rec, rra);
  prep_node<<<1049, 256, 0, stream>>>(at5_w1, at5_w2, o1_w, o2_w, o3_w, tnode);

  hipFuncSetAttribute((const void*)edge_kernel,
                      hipFuncAttributeMaxDynamicSharedMemorySize, LDS_EDGE_BYTES);
  edge_kernel<<<BT * 4, 512, LDS_EDGE_BYTES, stream>>>(
      x, rel_rec, rel_send, rel_type, mf1_w, mf1_b, mf2_b, at1_b1, at1_b2,
      at1_g, at1_be, wf, rra, g_agg);

  node_kernel<<<256, 256, 0, stream>>>(g_agg, x, tnode, tnode + 67600,
                                       tnode + 135200, tnode + 201760, tnode + 267296,
                                       at5_b1, at5_b2, at5_g, at5_be,
                                       o1_b, o2_b, o3_b, (float*)d_out);
}

// Round 7
// 463.101 us; speedup vs baseline: 1.6404x; 1.4170x over previous
//
#include <hip/hip_runtime.h>
#include <hip/hip_bf16.h>
#include <math.h>

typedef __bf16 bf16x8 __attribute__((ext_vector_type(8)));
typedef __bf16 bf16x4 __attribute__((ext_vector_type(4)));
typedef float f32x4 __attribute__((ext_vector_type(4)));

#define MFMA16(a,b,c) __builtin_amdgcn_mfma_f32_16x16x32_bf16(a,b,c,0,0,0)

static constexpr int Nn = 48, Hh = 256;
static constexpr int Ee = 2256, BT = 64;
static constexpr int ETILE = 64, NTILES = 36;          // 36*64 = 2304 >= 2256
static constexpr float BN_RS = 0.9999950000374998f;    // 1/sqrt(1+1e-5)

// ---- ws layout (bytes) ----
// wf: 4 mats (256x256) frag-linear bf16 @ mat*131072, + mf1 frags @ 524288+ty*16384
static constexpr size_t WS_WF  = 0;         // 557056
static constexpr size_t WS_RRA = 557056;    // 36*2*3*64*8 bf16 = 221184
static constexpr size_t WS_TN  = 778240;    // 268320 f32 = 1073280
static constexpr size_t WS_AGG = 1851520;   // g_agg [64][48][256] f32 = 3145728 (MODE0)
static constexpr size_t WS_PB  = 4997248;   // bf16 partials [256][48][256] = 6291456 (MODE1)
static constexpr size_t WS_NEED1 = WS_PB + 6291456;  // 11288704

// ---- LDS layout (bytes) ----
static constexpr int LDS_ACT = 0;        // [64][512B] swizzled act (fc1 out / at1_l1 out)
static constexpr int LDS_ALM = 32768;    // [64][512B] all_msgs act, then h_edges B-frags
static constexpr int LDS_WSG = 65536;    // 2 x 32KB double-buffered weight chunk (DMA dest)
static constexpr int LDS_PMA = 131072;   // [64][64B] pre_msg bf16, K=32 padded (k=8 is const 1.0)
static constexpr int LDS_RT  = 135168;   // [64][2] f32
static constexpr int LDS_BS  = 135680;   // 1536 f32 biases
static constexpr int LDS_XS  = 141824;   // 192 f32
static constexpr int LDS_EDGE_BYTES = 142592;

__device__ __forceinline__ float eluf(float v) { return v > 0.f ? v : __expf(v) - 1.f; }

typedef __attribute__((address_space(1))) const unsigned int as1_uint;
typedef __attribute__((address_space(3))) unsigned int as3_uint;
__device__ __forceinline__ void gload16(const void* g, void* l) {
  __builtin_amdgcn_global_load_lds((as1_uint*)g, (as3_uint*)l, 16, 0, 0);
}

__device__ __forceinline__ int aoff(int e, int colbyte) {
  return e * 512 + (colbyte ^ ((e & 7) << 4));
}

// K=256 GEMM: per wave 32 edges (2 m-tiles) x 64 cols (4 n-tiles).
// A from swizzled LDS tile at abase; B frag-linear in global, DMA double-buffered
// in 32KB (K=64) chunks, 1 barrier per chunk.
__device__ __forceinline__ void gemm256(char* smem, const char* wsrcb, int abase,
                                        int tid, int lane, int wv,
                                        int m0, int n0b, f32x4 acc[2][4]) {
  char* wsg = smem + LDS_WSG;
  const int so = wv * 1024 + lane * 16;
  const int ld = wv * 1024;
#pragma unroll
  for (int i = 0; i < 4; ++i)
    gload16(wsrcb + i * 8192 + so, wsg + i * 8192 + ld);
  __syncthreads();  // chunk0 landed; also covers pre-GEMM LDS writes by all waves
  const int kgb = (lane >> 4) * 16;
#pragma unroll
  for (int c = 0; c < 4; ++c) {
    const char* bb = wsg + (c & 1) * 32768;
    if (c < 3) {
      char* nb = wsg + ((c + 1) & 1) * 32768;
#pragma unroll
      for (int i = 0; i < 4; ++i)
        gload16(wsrcb + (c + 1) * 32768 + i * 8192 + so, nb + i * 8192 + ld);
    }
#pragma unroll
    for (int ks = 0; ks < 2; ++ks) {
      const int kt = c * 2 + ks;
      bf16x8 af[2];
#pragma unroll
      for (int mt = 0; mt < 2; ++mt) {
        int r = m0 + mt * 16 + (lane & 15);
        af[mt] = *(const bf16x8*)(smem + abase + r * 512 + ((kt * 64 + kgb) ^ ((r & 7) << 4)));
      }
#pragma unroll
      for (int nt = 0; nt < 4; ++nt) {
        bf16x8 bfr = *(const bf16x8*)(bb + ((ks * 16 + n0b + nt) * 64 + lane) * 16);
        acc[0][nt] = MFMA16(af[0], bfr, acc[0][nt]);
        acc[1][nt] = MFMA16(af[1], bfr, acc[1][nt]);
      }
    }
    __syncthreads();  // next chunk landed; current buf free
  }
}

template<int MODE>
__global__ __launch_bounds__(512)
void edge_kernel(const float* __restrict__ x, const float* __restrict__ rel_rec,
                 const float* __restrict__ rel_send, const float* __restrict__ rel_type,
                 const float* __restrict__ mf2_b, const float* __restrict__ at1_b1,
                 const float* __restrict__ at1_b2, const float* __restrict__ at1_g,
                 const float* __restrict__ at1_be, const __bf16* __restrict__ wf,
                 const __bf16* __restrict__ rra, float* __restrict__ g_agg,
                 __bf16* __restrict__ partb) {
  extern __shared__ char smem[];
  float* xs = (float*)(smem + LDS_XS);
  float* rt = (float*)(smem + LDS_RT);
  float* bs = (float*)(smem + LDS_BS);
  const char* wfb = (const char*)wf;

  const int tid = threadIdx.x;
  const int lane = tid & 63;
  const int wv = tid >> 6;
  const int lg = lane >> 4;
  const int col16 = lane & 15;
  const int wvM = wv & 1, wvN = wv >> 1;
  const int m0 = wvM * 32, n0 = wvN * 64, n0b = wvN * 4;
  const int slice = blockIdx.x >> 2;
  const int split = blockIdx.x & 3;
  const int t_begin = split * 9;

  // block-start preloads: xs, bias table, PMA zero+ones
  if (tid < Nn * 4) xs[tid] = x[slice * Nn * 4 + tid];
#pragma unroll
  for (int i = 0; i < 3; ++i) {
    int t = i * 512 + tid, which = t >> 8, o = t & 255;
    float v;
    switch (which) {
      case 0: v = mf2_b[o]; break;
      case 1: v = mf2_b[256 + o]; break;
      case 2: v = at1_b1[o]; break;
      case 3: v = at1_b2[o]; break;
      case 4: v = at1_g[o] * BN_RS; break;
      default: v = at1_be[o]; break;
    }
    bs[t] = v;
  }
  // PMA: zeros, with bf16 1.0 at k=8 of each row (bias lane).
  // NOTE: 1024 uints, 512 threads -> grid-stride (round-6 bug: `if (tid<1024)`
  // left rows 32..63 uninitialized -> garbage k=8 column -> absmax 3e36).
#pragma unroll
  for (int t = tid; t < 1024; t += 512)
    ((unsigned int*)(smem + LDS_PMA))[t] = ((t & 15) == 4) ? 0x00003f80u : 0u;

  f32x4 ag[3][2];
#pragma unroll
  for (int a = 0; a < 3; ++a)
#pragma unroll
    for (int b = 0; b < 2; ++b) ag[a][b] = (f32x4){0.f, 0.f, 0.f, 0.f};
  __syncthreads();

  for (int tt = 0; tt < 9; ++tt) {
    const int tile = t_begin + tt;
    const int e0 = tile * ETILE;
    const int ne = (Ee - e0 < ETILE) ? (Ee - e0) : ETILE;

    // rel_type tile
    if (tid < ETILE * 2) {
      int e = tid >> 1, i2 = tid & 1;
      rt[tid] = (e < ne) ? rel_type[((size_t)slice * Ee + e0 + e) * 2 + i2] : 0.f;
    }
    // pre_msg -> PMA bf16 (k-cols 0..7; col 8 stays 1.0 for bias)
    {
      int c = tid >> 6, e = tid & 63;
      float s = 0.f;
      if (e < ne) {
        const float* rel = ((c < 4) ? rel_send : rel_rec) + (size_t)(e0 + e) * Nn;
        int f = c & 3;
#pragma unroll
        for (int n = 0; n < Nn; ++n) s += rel[n] * xs[n * 4 + f];
      }
      *(__bf16*)(smem + LDS_PMA + e * 64 + c * 2) = (__bf16)s;
    }

    f32x4 allm[2][4];
#pragma unroll
    for (int mt = 0; mt < 2; ++mt)
#pragma unroll
      for (int nt = 0; nt < 4; ++nt) allm[mt][nt] = (f32x4){0.f, 0.f, 0.f, 0.f};

    for (int ty = 0; ty < 2; ++ty) {
      // fc1 as MFMA: A = PMA [64][32] (bias folded at k=8), B = mf1 frags (16KB)
      {
        const char* src = wfb + 524288 + ty * 16384;
        char* buf1 = smem + LDS_WSG + 32768;
#pragma unroll
        for (int i = 0; i < 2; ++i)
          gload16(src + i * 8192 + wv * 1024 + lane * 16, buf1 + i * 8192 + wv * 1024);
        __syncthreads();  // frags + PMA + rt visible
        f32x4 fa[2][4];
#pragma unroll
        for (int mt = 0; mt < 2; ++mt)
#pragma unroll
          for (int nt = 0; nt < 4; ++nt) fa[mt][nt] = (f32x4){0.f, 0.f, 0.f, 0.f};
        bf16x8 af[2];
#pragma unroll
        for (int mt = 0; mt < 2; ++mt) {
          int r = m0 + mt * 16 + col16;
          af[mt] = *(const bf16x8*)(smem + LDS_PMA + r * 64 + lg * 16);
        }
#pragma unroll
        for (int nt = 0; nt < 4; ++nt) {
          bf16x8 bfr = *(const bf16x8*)(buf1 + ((n0b + nt) * 64 + lane) * 16);
          fa[0][nt] = MFMA16(af[0], bfr, fa[0][nt]);
          fa[1][nt] = MFMA16(af[1], bfr, fa[1][nt]);
        }
        // relu -> ACT (swizzled act layout)
#pragma unroll
        for (int mt = 0; mt < 2; ++mt)
#pragma unroll
          for (int nt = 0; nt < 4; ++nt) {
            int cb = (n0 + nt * 16 + col16) * 2;
#pragma unroll
            for (int r = 0; r < 4; ++r) {
              int e = m0 + mt * 16 + lg * 4 + r;
              *(__bf16*)(smem + LDS_ACT + aoff(e, cb)) = (__bf16)fmaxf(fa[mt][nt][r], 0.f);
            }
          }
      }
      // mf2[ty]: ACT @ W -> relu(+b) * rel_type, accumulate in regs
      f32x4 acc[2][4];
#pragma unroll
      for (int mt = 0; mt < 2; ++mt)
#pragma unroll
        for (int nt = 0; nt < 4; ++nt) acc[mt][nt] = (f32x4){0.f, 0.f, 0.f, 0.f};
      gemm256(smem, wfb + (size_t)ty * 131072, LDS_ACT, tid, lane, wv, m0, n0b, acc);
      const float* bb2 = bs + ty * 256;
#pragma unroll
      for (int mt = 0; mt < 2; ++mt) {
        float rtv[4];
#pragma unroll
        for (int r = 0; r < 4; ++r) rtv[r] = rt[(m0 + mt * 16 + lg * 4 + r) * 2 + ty];
#pragma unroll
        for (int nt = 0; nt < 4; ++nt) {
          float bbv = bb2[n0 + nt * 16 + col16];
#pragma unroll
          for (int r = 0; r < 4; ++r)
            allm[mt][nt][r] += fmaxf(acc[mt][nt][r] + bbv, 0.f) * rtv[r];
        }
      }
    }

    // all_msgs regs -> ALM (swizzled act layout)
#pragma unroll
    for (int mt = 0; mt < 2; ++mt)
#pragma unroll
      for (int nt = 0; nt < 4; ++nt) {
        int cb = (n0 + nt * 16 + col16) * 2;
#pragma unroll
        for (int r = 0; r < 4; ++r) {
          int e = m0 + mt * 16 + lg * 4 + r;
          *(__bf16*)(smem + LDS_ALM + aoff(e, cb)) = (__bf16)allm[mt][nt][r];
        }
      }

    // at1_l1: ALM @ W -> elu -> ACT
    {
      f32x4 acc[2][4];
#pragma unroll
      for (int mt = 0; mt < 2; ++mt)
#pragma unroll
        for (int nt = 0; nt < 4; ++nt) acc[mt][nt] = (f32x4){0.f, 0.f, 0.f, 0.f};
      gemm256(smem, wfb + (size_t)2 * 131072, LDS_ALM, tid, lane, wv, m0, n0b, acc);
      const float* bb2 = bs + 512;
#pragma unroll
      for (int mt = 0; mt < 2; ++mt)
#pragma unroll
        for (int nt = 0; nt < 4; ++nt) {
          float bbv = bb2[n0 + nt * 16 + col16];
          int cb = (n0 + nt * 16 + col16) * 2;
#pragma unroll
          for (int r = 0; r < 4; ++r) {
            int e = m0 + mt * 16 + lg * 4 + r;
            *(__bf16*)(smem + LDS_ACT + aoff(e, cb)) = (__bf16)eluf(acc[mt][nt][r] + bbv);
          }
        }
    }

    // at1_l2: ACT @ W -> elu*sc+be -> h_edges B-frags in ALM
    {
      f32x4 acc[2][4];
#pragma unroll
      for (int mt = 0; mt < 2; ++mt)
#pragma unroll
        for (int nt = 0; nt < 4; ++nt) acc[mt][nt] = (f32x4){0.f, 0.f, 0.f, 0.f};
      gemm256(smem, wfb + (size_t)3 * 131072, LDS_ACT, tid, lane, wv, m0, n0b, acc);
      const float* bb2 = bs + 768;
      const float* scv = bs + 1024;
      const float* bev = bs + 1280;
      const int j0 = (lg & 1) * 4;
#pragma unroll
      for (int mt = 0; mt < 2; ++mt) {
        const int lane2 = col16 | ((mt * 2 + (lg >> 1)) << 4);
#pragma unroll
        for (int nt = 0; nt < 4; ++nt) {
          int col = n0 + nt * 16 + col16;
          float b_ = bb2[col], s1 = scv[col], s2 = bev[col];
          bf16x4 pk;
#pragma unroll
          for (int r = 0; r < 4; ++r)
            pk[r] = (__bf16)(eluf(acc[mt][nt][r] + b_) * s1 + s2);
          int addr = (((wvM * 16 + n0b + nt) * 64 + lane2) * 8 + j0) * 2;
          *(bf16x4*)(smem + LDS_ALM + addr) = pk;
        }
      }
    }
    __syncthreads();  // B-frags visible

    // agg GEMM: ag += rel_rec[tile]^T @ h_edges  (M=48, N=256, K=64)
    const bf16x8* rraw = (const bf16x8*)rra + (size_t)tile * 384;
#pragma unroll
    for (int kt2 = 0; kt2 < 2; ++kt2) {
      bf16x8 b0 = *(const bf16x8*)(smem + LDS_ALM + ((kt2 * 16 + wv * 2 + 0) * 64 + lane) * 16);
      bf16x8 b1 = *(const bf16x8*)(smem + LDS_ALM + ((kt2 * 16 + wv * 2 + 1) * 64 + lane) * 16);
#pragma unroll
      for (int mt2 = 0; mt2 < 3; ++mt2) {
        bf16x8 a = rraw[(kt2 * 3 + mt2) * 64 + lane];
        ag[mt2][0] = MFMA16(a, b0, ag[mt2][0]);
        ag[mt2][1] = MFMA16(a, b1, ag[mt2][1]);
      }
    }
    // no barrier needed: next writers of ALM/ACT are gated by later barriers
  }

  if (MODE == 1) {
    __bf16* dst = partb + (size_t)blockIdx.x * Nn * Hh;
#pragma unroll
    for (int mt2 = 0; mt2 < 3; ++mt2)
#pragma unroll
      for (int ntl = 0; ntl < 2; ++ntl) {
        int h = (wv * 2 + ntl) * 16 + col16;
#pragma unroll
        for (int r = 0; r < 4; ++r) {
          int n = mt2 * 16 + lg * 4 + r;
          dst[n * Hh + h] = (__bf16)ag[mt2][ntl][r];
        }
      }
  } else {
    float* dst = g_agg + (size_t)slice * Nn * Hh;
#pragma unroll
    for (int mt2 = 0; mt2 < 3; ++mt2)
#pragma unroll
      for (int ntl = 0; ntl < 2; ++ntl) {
        int h = (wv * 2 + ntl) * 16 + col16;
#pragma unroll
        for (int r = 0; r < 4; ++r) {
          int n = mt2 * 16 + lg * 4 + r;
          atomicAdd(dst + n * Hh + h, ag[mt2][ntl][r]);
        }
      }
  }
}

// 4 weight matrices [256][256] fp32 -> bf16 MFMA B-fragment-linear
__global__ void prep_frag(const float* __restrict__ mf2_w, const float* __restrict__ at1_w1,
                          const float* __restrict__ at1_w2, __bf16* __restrict__ wfdst) {
  int id = blockIdx.x * 256 + threadIdx.x;  // 32768 total
  int mat = id >> 13, r = id & 8191;
  int kt = r >> 10, q = r & 1023, nt = q >> 6, l = q & 63;
  int row = nt * 16 + (l & 15), col = kt * 32 + (l >> 4) * 8;
  const float* src = (mat == 0) ? mf2_w : (mat == 1) ? (mf2_w + 65536)
                   : (mat == 2) ? at1_w1 : at1_w2;
  const float* p = src + row * 256 + col;
  __bf16* d = wfdst + (size_t)mat * 65536 + ((size_t)(kt * 16 + nt) * 64 + l) * 8;
#pragma unroll
  for (int j = 0; j < 8; ++j) d[j] = (__bf16)p[j];
}

// mf1 (2F=8 -> H=256) as K=32-padded B-frags; bias folded at k=8
__global__ void prep_mf1(const float* __restrict__ mf1_w, const float* __restrict__ mf1_b,
                         __bf16* __restrict__ wfdst) {
  int id = blockIdx.x * 256 + threadIdx.x;  // 2048 total
  int ty = id >> 10, q = id & 1023, ntg = q >> 6, l = q & 63;
  int col = ntg * 16 + (l & 15);
  int k0 = (l >> 4) * 8;
  bf16x8 v;
#pragma unroll
  for (int j = 0; j < 8; ++j) {
    int k = k0 + j;
    float x = (k < 8) ? mf1_w[ty * 2048 + col * 8 + k]
            : (k == 8) ? mf1_b[ty * 256 + col] : 0.f;
    v[j] = (__bf16)x;
  }
  ((bf16x8*)(wfdst + 262144))[id] = v;
}

// rel_rec^T per-tile bf16 A-fragments: rra[tile][kt2(2)][mt2(3)][lane][8]
__global__ void prep_rra(const float* __restrict__ rel_rec, __bf16* __restrict__ rra) {
  int id = blockIdx.x * 256 + threadIdx.x;  // 36*384 = 13824
  if (id >= 13824) return;
  int tile = id / 384, r = id % 384;
  int kt2 = r / 192, r2 = r % 192, mt2 = r2 >> 6, l = r2 & 63;
  int ebase = tile * 64 + kt2 * 32 + (l >> 4) * 8;
  int n = mt2 * 16 + (l & 15);
  bf16x8 v;
#pragma unroll
  for (int j = 0; j < 8; ++j) {
    int e = ebase + j;
    v[j] = (__bf16)((e < Ee) ? rel_rec[(size_t)e * Nn + n] : 0.f);
  }
  ((bf16x8*)rra)[id] = v;
}

// transpose node-side weights (fp32) for coalesced lane reads
__global__ void prep_node(const float* __restrict__ at5_w1, const float* __restrict__ at5_w2,
                          const float* __restrict__ o1_w, const float* __restrict__ o2_w,
                          const float* __restrict__ o3_w, float* __restrict__ ws) {
  int id = blockIdx.x * 256 + threadIdx.x;
  float* T1 = ws;
  float* T2 = T1 + 67600;
  float* To1 = T2 + 67600;
  float* To2 = To1 + 66560;
  float* To3 = To2 + 65536;
  if (id < 67600) { int o = id % 260, k = id / 260; T1[k * 260 + o] = at5_w1[o * 260 + k]; return; }
  id -= 67600;
  if (id < 67600) { int o = id % 260, k = id / 260; T2[k * 260 + o] = at5_w2[o * 260 + k]; return; }
  id -= 67600;
  if (id < 66560) { int o = id & 255, k = id >> 8; To1[k * 256 + o] = o1_w[o * 260 + k]; return; }
  id -= 66560;
  if (id < 65536) { int o = id & 255, k = id >> 8; To2[k * 256 + o] = o2_w[o * 256 + k]; return; }
  id -= 65536;
  if (id < 1024) { int f = id & 3, k = id >> 2; To3[k * 4 + f] = o3_w[f * 256 + k]; }
}

template<int MODE>
__global__ __launch_bounds__(256, 4)
void node_kernel(const float* __restrict__ g_agg, const __bf16* __restrict__ partb,
                 const float* __restrict__ x,
                 const float* __restrict__ T1, const float* __restrict__ T2,
                 const float* __restrict__ To1, const float* __restrict__ To2,
                 const float* __restrict__ To3, const float* __restrict__ at5_b1,
                 const float* __restrict__ at5_b2, const float* __restrict__ at5_g,
                 const float* __restrict__ at5_be, const float* __restrict__ o1_b,
                 const float* __restrict__ o2_b, const float* __restrict__ o3_b,
                 float* __restrict__ out) {
  __shared__ float bufA[12 * 264], bufB[12 * 264], xres[12 * 4];
  const int tid = threadIdx.x;
  const int slice = blockIdx.x >> 2, rg = blockIdx.x & 3;
  const int n0 = rg * 12;
  for (int t = tid; t < 12 * 256; t += 256) {
    int r = t >> 8, h = t & 255;
    float s;
    if (MODE == 1) {
      s = 0.f;
#pragma unroll
      for (int sp = 0; sp < 4; ++sp)
        s += (float)partb[(((size_t)slice * 4 + sp) * Nn + n0 + r) * Hh + h];
    } else {
      s = g_agg[(size_t)slice * 12288 + (size_t)(n0 + r) * 256 + h];
    }
    bufA[r * 264 + h] = s;
  }
  if (tid < 48) {
    int r = tid >> 2, f = tid & 3;
    float v = x[(size_t)slice * 192 + (n0 + r) * 4 + f];
    bufA[r * 264 + 256 + f] = v;
    xres[tid] = v;
  }
  __syncthreads();

  auto layer = [&](const float* WT, const float* bsrc, const float* in, float* outb,
                   int K, int O, int act, const float* gsc, const float* gbe) {
    for (int o = tid; o < O; o += 256) {
      float a[12];
      float bb = bsrc[o];
#pragma unroll
      for (int r = 0; r < 12; ++r) a[r] = bb;
      for (int k = 0; k < K; ++k) {
        float w = WT[k * O + o];
#pragma unroll
        for (int r = 0; r < 12; ++r) a[r] = fmaf(in[r * 264 + k], w, a[r]);
      }
      float scv = 1.f, bev = 0.f;
      if (act == 2) { scv = gsc[o] * BN_RS; bev = gbe[o]; }
#pragma unroll
      for (int r = 0; r < 12; ++r) {
        float v = a[r];
        v = (act == 0) ? fmaxf(v, 0.f) : eluf(v);
        if (act == 2) v = v * scv + bev;
        outb[r * 264 + o] = v;
      }
    }
    __syncthreads();
  };

  layer(T1, at5_b1, bufA, bufB, 260, 260, 1, nullptr, nullptr);
  layer(T2, at5_b2, bufB, bufA, 260, 260, 2, at5_g, at5_be);
  layer(To1, o1_b, bufA, bufB, 260, 256, 0, nullptr, nullptr);
  layer(To2, o2_b, bufB, bufA, 256, 256, 0, nullptr, nullptr);
  if (tid < 48) {
    int r = tid >> 2, f = tid & 3;
    float s = o3_b[f];
    for (int k = 0; k < 256; ++k) s = fmaf(bufA[r * 264 + k], To3[k * 4 + f], s);
    out[(size_t)slice * 192 + (n0 + r) * 4 + f] = xres[tid] + s;
  }
}

extern "C" void kernel_launch(void* const* d_in, const int* in_sizes, int n_in,
                              void* d_out, int out_size, void* d_ws, size_t ws_size,
                              hipStream_t stream) {
  const float* x = (const float*)d_in[0];
  const float* rel_rec = (const float*)d_in[1];
  const float* rel_send = (const float*)d_in[2];
  const float* rel_type = (const float*)d_in[3];
  const float* mf1_w = (const float*)d_in[4];
  const float* mf1_b = (const float*)d_in[5];
  const float* mf2_w = (const float*)d_in[6];
  const float* mf2_b = (const float*)d_in[7];
  const float* at1_w1 = (const float*)d_in[8];
  const float* at1_b1 = (const float*)d_in[9];
  const float* at1_w2 = (const float*)d_in[10];
  const float* at1_b2 = (const float*)d_in[11];
  const float* at1_g = (const float*)d_in[12];
  const float* at1_be = (const float*)d_in[13];
  const float* at5_w1 = (const float*)d_in[14];
  const float* at5_b1 = (const float*)d_in[15];
  const float* at5_w2 = (const float*)d_in[16];
  const float* at5_b2 = (const float*)d_in[17];
  const float* at5_g = (const float*)d_in[18];
  const float* at5_be = (const float*)d_in[19];
  const float* o1_w = (const float*)d_in[20];
  const float* o1_b = (const float*)d_in[21];
  const float* o2_w = (const float*)d_in[22];
  const float* o2_b = (const float*)d_in[23];
  const float* o3_w = (const float*)d_in[24];
  const float* o3_b = (const float*)d_in[25];

  char* ws = (char*)d_ws;
  __bf16* wf = (__bf16*)(ws + WS_WF);
  __bf16* rra = (__bf16*)(ws + WS_RRA);
  float* tnode = (float*)(ws + WS_TN);
  float* g_agg = (float*)(ws + WS_AGG);
  __bf16* partb = (__bf16*)(ws + WS_PB);

  const int mode = (ws_size >= WS_NEED1) ? 1 : 0;

  prep_frag<<<128, 256, 0, stream>>>(mf2_w, at1_w1, at1_w2, wf);
  prep_mf1<<<8, 256, 0, stream>>>(mf1_w, mf1_b, wf);
  prep_rra<<<54, 256, 0, stream>>>(rel_rec, rra);
  prep_node<<<1049, 256, 0, stream>>>(at5_w1, at5_w2, o1_w, o2_w, o3_w, tnode);

  if (mode == 1) {
    hipFuncSetAttribute((const void*)edge_kernel<1>,
                        hipFuncAttributeMaxDynamicSharedMemorySize, LDS_EDGE_BYTES);
    edge_kernel<1><<<BT * 4, 512, LDS_EDGE_BYTES, stream>>>(
        x, rel_rec, rel_send, rel_type, mf2_b, at1_b1, at1_b2,
        at1_g, at1_be, wf, rra, g_agg, partb);
    node_kernel<1><<<256, 256, 0, stream>>>(g_agg, partb, x, tnode, tnode + 67600,
                                            tnode + 135200, tnode + 201760, tnode + 267296,
                                            at5_b1, at5_b2, at5_g, at5_be,
                                            o1_b, o2_b, o3_b, (float*)d_out);
  } else {
    hipMemsetAsync(g_agg, 0, (size_t)BT * Nn * Hh * 4, stream);
    hipFuncSetAttribute((const void*)edge_kernel<0>,
                        hipFuncAttributeMaxDynamicSharedMemorySize, LDS_EDGE_BYTES);
    edge_kernel<0><<<BT * 4, 512, LDS_EDGE_BYTES, stream>>>(
        x, rel_rec, rel_send, rel_type, mf2_b, at1_b1, at1_b2,
        at1_g, at1_be, wf, rra, g_agg, partb);
    node_kernel<0><<<256, 256, 0, stream>>>(g_agg, partb, x, tnode, tnode + 67600,
                                            tnode + 135200, tnode + 201760, tnode + 267296,
                                            at5_b1, at5_b2, at5_g, at5_be,
                                            o1_b, o2_b, o3_b, (float*)d_out);
  }
}

// Round 8
// 333.395 us; speedup vs baseline: 2.2786x; 1.3890x over previous
//
#include <hip/hip_runtime.h>
#include <hip/hip_bf16.h>
#include <math.h>

typedef __bf16 bf16x8 __attribute__((ext_vector_type(8)));
typedef __bf16 bf16x4 __attribute__((ext_vector_type(4)));
typedef float f32x4 __attribute__((ext_vector_type(4)));

#define MFMA16(a,b,c) __builtin_amdgcn_mfma_f32_16x16x32_bf16(a,b,c,0,0,0)

static constexpr int Nn = 48, Hh = 256;
static constexpr int Ee = 2256, BT = 64;
static constexpr int ETILE = 64, NTILES = 36;          // 36*64 = 2304 >= 2256
static constexpr float BN_RS = 0.9999950000374998f;    // 1/sqrt(1+1e-5)

// ---- ws layout (bytes) ----
static constexpr size_t WS_WF  = 0;         // 4 mats frag-linear + mf1 frags: 557056
static constexpr size_t WS_RRA = 557056;    // 36*2*3*64*8 bf16 = 221184
static constexpr size_t WS_TN  = 778240;    // 268320 f32 = 1073280
static constexpr size_t WS_AGG = 1851520;   // g_agg [64][48][256] f32 = 3145728 (MODE0)
static constexpr size_t WS_PB  = 4997248;   // bf16 partials [256][48][256] = 6291456 (MODE1)
static constexpr size_t WS_NEED1 = WS_PB + 6291456;  // 11288704

// ---- LDS layout (bytes) ----
static constexpr int LDS_ACT = 0;        // [64][512B] swizzled act (fc1 out / at1_l1 out)
static constexpr int LDS_ALM = 32768;    // [64][512B] all_msgs act, then h_edges B-frags
static constexpr int LDS_WSG = 65536;    // 2 x 32KB double-buffered weight chunk (DMA dest)
static constexpr int LDS_PMA = 131072;   // [64][64B] pre_msg bf16, K=32 padded (k=8 const 1.0)
static constexpr int LDS_RT  = 135168;   // [64][2] f32
static constexpr int LDS_BS  = 135680;   // 1536 f32 biases
static constexpr int LDS_XS  = 141824;   // 192 f32
static constexpr int LDS_EDGE_BYTES = 142592;

__device__ __forceinline__ float eluf(float v) { return v > 0.f ? v : __expf(v) - 1.f; }

typedef __attribute__((address_space(1))) const unsigned int as1_uint;
typedef __attribute__((address_space(3))) unsigned int as3_uint;
__device__ __forceinline__ void gload16(const void* g, void* l) {
  __builtin_amdgcn_global_load_lds((as1_uint*)g, (as3_uint*)l, 16, 0, 0);
}

__device__ __forceinline__ int aoff(int e, int colbyte) {
  return e * 512 + (colbyte ^ ((e & 7) << 4));
}

// K=256 GEMM: per wave 32 edges (2 m-tiles) x 64 cols (4 n-tiles).
// A from swizzled LDS tile at abase; B frag-linear in global, DMA double-buffered
// in 32KB (K=64) chunks, 1 barrier per chunk.
__device__ __forceinline__ void gemm256(char* smem, const char* wsrcb, int abase,
                                        int tid, int lane, int wv,
                                        int m0, int n0b, f32x4 acc[2][4]) {
  char* wsg = smem + LDS_WSG;
  const int so = wv * 1024 + lane * 16;
  const int ld = wv * 1024;
#pragma unroll
  for (int i = 0; i < 4; ++i)
    gload16(wsrcb + i * 8192 + so, wsg + i * 8192 + ld);
  __syncthreads();  // chunk0 landed; also covers pre-GEMM LDS writes by all waves
  const int kgb = (lane >> 4) * 16;
#pragma unroll
  for (int c = 0; c < 4; ++c) {
    const char* bb = wsg + (c & 1) * 32768;
    if (c < 3) {
      char* nb = wsg + ((c + 1) & 1) * 32768;
#pragma unroll
      for (int i = 0; i < 4; ++i)
        gload16(wsrcb + (c + 1) * 32768 + i * 8192 + so, nb + i * 8192 + ld);
    }
#pragma unroll
    for (int ks = 0; ks < 2; ++ks) {
      const int kt = c * 2 + ks;
      bf16x8 af[2];
#pragma unroll
      for (int mt = 0; mt < 2; ++mt) {
        int r = m0 + mt * 16 + (lane & 15);
        af[mt] = *(const bf16x8*)(smem + abase + r * 512 + ((kt * 64 + kgb) ^ ((r & 7) << 4)));
      }
#pragma unroll
      for (int nt = 0; nt < 4; ++nt) {
        bf16x8 bfr = *(const bf16x8*)(bb + ((ks * 16 + n0b + nt) * 64 + lane) * 16);
        acc[0][nt] = MFMA16(af[0], bfr, acc[0][nt]);
        acc[1][nt] = MFMA16(af[1], bfr, acc[1][nt]);
      }
    }
    __syncthreads();  // next chunk landed; current buf free
  }
}

template<int MODE>
__global__ __launch_bounds__(512)
void edge_kernel(const float* __restrict__ x, const float* __restrict__ rel_rec,
                 const float* __restrict__ rel_send, const float* __restrict__ rel_type,
                 const float* __restrict__ mf2_b, const float* __restrict__ at1_b1,
                 const float* __restrict__ at1_b2, const float* __restrict__ at1_g,
                 const float* __restrict__ at1_be, const __bf16* __restrict__ wf,
                 const __bf16* __restrict__ rra, float* __restrict__ g_agg,
                 __bf16* __restrict__ partb) {
  extern __shared__ char smem[];
  float* xs = (float*)(smem + LDS_XS);
  float* rt = (float*)(smem + LDS_RT);
  float* bs = (float*)(smem + LDS_BS);
  const char* wfb = (const char*)wf;

  const int tid = threadIdx.x;
  const int lane = tid & 63;
  const int wv = tid >> 6;
  const int lg = lane >> 4;
  const int col16 = lane & 15;
  const int wvM = wv & 1, wvN = wv >> 1;
  const int m0 = wvM * 32, n0 = wvN * 64, n0b = wvN * 4;
  const int slice = blockIdx.x >> 2;
  const int split = blockIdx.x & 3;
  const int t_begin = split * 9;

  // block-start preloads: xs, bias table, PMA zero+ones
  if (tid < Nn * 4) xs[tid] = x[slice * Nn * 4 + tid];
#pragma unroll
  for (int i = 0; i < 3; ++i) {
    int t = i * 512 + tid, which = t >> 8, o = t & 255;
    float v;
    switch (which) {
      case 0: v = mf2_b[o]; break;
      case 1: v = mf2_b[256 + o]; break;
      case 2: v = at1_b1[o]; break;
      case 3: v = at1_b2[o]; break;
      case 4: v = at1_g[o] * BN_RS; break;
      default: v = at1_be[o]; break;
    }
    bs[t] = v;
  }
  // PMA: zeros, with bf16 1.0 at k=8 of each row (grid-stride: 1024 uints, 512 thr)
#pragma unroll
  for (int t = tid; t < 1024; t += 512)
    ((unsigned int*)(smem + LDS_PMA))[t] = ((t & 15) == 4) ? 0x00003f80u : 0u;

  f32x4 ag[3][2];
#pragma unroll
  for (int a = 0; a < 3; ++a)
#pragma unroll
    for (int b = 0; b < 2; ++b) ag[a][b] = (f32x4){0.f, 0.f, 0.f, 0.f};
  __syncthreads();

  for (int tt = 0; tt < 9; ++tt) {
    const int tile = t_begin + tt;
    const int e0 = tile * ETILE;
    const int ne = (Ee - e0 < ETILE) ? (Ee - e0) : ETILE;

    // rel_type tile
    if (tid < ETILE * 2) {
      int e = tid >> 1, i2 = tid & 1;
      rt[tid] = (e < ne) ? rel_type[((size_t)slice * Ee + e0 + e) * 2 + i2] : 0.f;
    }
    // pre_msg -> PMA bf16 (k-cols 0..7; col 8 stays 1.0 for bias)
    {
      int c = tid >> 6, e = tid & 63;
      float s = 0.f;
      if (e < ne) {
        const float* rel = ((c < 4) ? rel_send : rel_rec) + (size_t)(e0 + e) * Nn;
        int f = c & 3;
#pragma unroll
        for (int n = 0; n < Nn; ++n) s += rel[n] * xs[n * 4 + f];
      }
      *(__bf16*)(smem + LDS_PMA + e * 64 + c * 2) = (__bf16)s;
    }

    // per-edge-type: fc1 (MFMA, bias folded) -> mf2 GEMM -> relu*rt, accum in ALM (bf16)
#pragma unroll 1
    for (int ty = 0; ty < 2; ++ty) {
      {
        const char* src = wfb + 524288 + ty * 16384;
        char* buf1 = smem + LDS_WSG + 32768;
#pragma unroll
        for (int i = 0; i < 2; ++i)
          gload16(src + i * 8192 + wv * 1024 + lane * 16, buf1 + i * 8192 + wv * 1024);
        __syncthreads();  // frags + PMA + rt visible
        f32x4 fa[2][4];
#pragma unroll
        for (int mt = 0; mt < 2; ++mt)
#pragma unroll
          for (int nt = 0; nt < 4; ++nt) fa[mt][nt] = (f32x4){0.f, 0.f, 0.f, 0.f};
        bf16x8 af[2];
#pragma unroll
        for (int mt = 0; mt < 2; ++mt) {
          int r = m0 + mt * 16 + col16;
          af[mt] = *(const bf16x8*)(smem + LDS_PMA + r * 64 + lg * 16);
        }
#pragma unroll
        for (int nt = 0; nt < 4; ++nt) {
          bf16x8 bfr = *(const bf16x8*)(buf1 + ((n0b + nt) * 64 + lane) * 16);
          fa[0][nt] = MFMA16(af[0], bfr, fa[0][nt]);
          fa[1][nt] = MFMA16(af[1], bfr, fa[1][nt]);
        }
        // relu -> ACT (swizzled act layout)
#pragma unroll
        for (int mt = 0; mt < 2; ++mt)
#pragma unroll
          for (int nt = 0; nt < 4; ++nt) {
            int cb = (n0 + nt * 16 + col16) * 2;
#pragma unroll
            for (int r = 0; r < 4; ++r) {
              int e = m0 + mt * 16 + lg * 4 + r;
              *(__bf16*)(smem + LDS_ACT + aoff(e, cb)) = (__bf16)fmaxf(fa[mt][nt][r], 0.f);
            }
          }
      }
      // mf2[ty]: ACT @ W; epilogue accumulates into ALM (no allm registers)
      f32x4 acc[2][4];
#pragma unroll
      for (int mt = 0; mt < 2; ++mt)
#pragma unroll
        for (int nt = 0; nt < 4; ++nt) acc[mt][nt] = (f32x4){0.f, 0.f, 0.f, 0.f};
      gemm256(smem, wfb + (size_t)ty * 131072, LDS_ACT, tid, lane, wv, m0, n0b, acc);
      const float* bb2 = bs + ty * 256;
#pragma unroll
      for (int mt = 0; mt < 2; ++mt) {
        float rtv[4];
#pragma unroll
        for (int r = 0; r < 4; ++r) rtv[r] = rt[(m0 + mt * 16 + lg * 4 + r) * 2 + ty];
#pragma unroll
        for (int nt = 0; nt < 4; ++nt) {
          float bbv = bb2[n0 + nt * 16 + col16];
          int cb = (n0 + nt * 16 + col16) * 2;
#pragma unroll
          for (int r = 0; r < 4; ++r) {
            int e = m0 + mt * 16 + lg * 4 + r;
            float v = fmaxf(acc[mt][nt][r] + bbv, 0.f) * rtv[r];
            __bf16* p = (__bf16*)(smem + LDS_ALM + aoff(e, cb));
            if (ty == 1) v += (float)*p;  // own patch: same thread wrote it at ty=0
            *p = (__bf16)v;
          }
        }
      }
    }

    // at1_l1: ALM @ W -> elu -> ACT
    {
      f32x4 acc[2][4];
#pragma unroll
      for (int mt = 0; mt < 2; ++mt)
#pragma unroll
        for (int nt = 0; nt < 4; ++nt) acc[mt][nt] = (f32x4){0.f, 0.f, 0.f, 0.f};
      gemm256(smem, wfb + (size_t)2 * 131072, LDS_ALM, tid, lane, wv, m0, n0b, acc);
      const float* bb2 = bs + 512;
#pragma unroll
      for (int mt = 0; mt < 2; ++mt)
#pragma unroll
        for (int nt = 0; nt < 4; ++nt) {
          float bbv = bb2[n0 + nt * 16 + col16];
          int cb = (n0 + nt * 16 + col16) * 2;
#pragma unroll
          for (int r = 0; r < 4; ++r) {
            int e = m0 + mt * 16 + lg * 4 + r;
            *(__bf16*)(smem + LDS_ACT + aoff(e, cb)) = (__bf16)eluf(acc[mt][nt][r] + bbv);
          }
        }
    }

    // at1_l2: ACT @ W -> elu*sc+be -> h_edges B-frags in ALM
    {
      f32x4 acc[2][4];
#pragma unroll
      for (int mt = 0; mt < 2; ++mt)
#pragma unroll
        for (int nt = 0; nt < 4; ++nt) acc[mt][nt] = (f32x4){0.f, 0.f, 0.f, 0.f};
      gemm256(smem, wfb + (size_t)3 * 131072, LDS_ACT, tid, lane, wv, m0, n0b, acc);
      const float* bb2 = bs + 768;
      const float* scv = bs + 1024;
      const float* bev = bs + 1280;
      const int j0 = (lg & 1) * 4;
#pragma unroll
      for (int mt = 0; mt < 2; ++mt) {
        const int lane2 = col16 | ((mt * 2 + (lg >> 1)) << 4);
#pragma unroll
        for (int nt = 0; nt < 4; ++nt) {
          int col = n0 + nt * 16 + col16;
          float b_ = bb2[col], s1 = scv[col], s2 = bev[col];
          bf16x4 pk;
#pragma unroll
          for (int r = 0; r < 4; ++r)
            pk[r] = (__bf16)(eluf(acc[mt][nt][r] + b_) * s1 + s2);
          int addr = (((wvM * 16 + n0b + nt) * 64 + lane2) * 8 + j0) * 2;
          *(bf16x4*)(smem + LDS_ALM + addr) = pk;
        }
      }
    }
    __syncthreads();  // B-frags visible

    // agg GEMM: ag += rel_rec[tile]^T @ h_edges  (M=48, N=256, K=64)
    const bf16x8* rraw = (const bf16x8*)rra + (size_t)tile * 384;
#pragma unroll
    for (int kt2 = 0; kt2 < 2; ++kt2) {
      bf16x8 b0 = *(const bf16x8*)(smem + LDS_ALM + ((kt2 * 16 + wv * 2 + 0) * 64 + lane) * 16);
      bf16x8 b1 = *(const bf16x8*)(smem + LDS_ALM + ((kt2 * 16 + wv * 2 + 1) * 64 + lane) * 16);
#pragma unroll
      for (int mt2 = 0; mt2 < 3; ++mt2) {
        bf16x8 a = rraw[(kt2 * 3 + mt2) * 64 + lane];
        ag[mt2][0] = MFMA16(a, b0, ag[mt2][0]);
        ag[mt2][1] = MFMA16(a, b1, ag[mt2][1]);
      }
    }
    // no barrier needed: next writers of ALM/ACT are gated by later barriers
  }

  if (MODE == 1) {
    __bf16* dst = partb + (size_t)blockIdx.x * Nn * Hh;
#pragma unroll
    for (int mt2 = 0; mt2 < 3; ++mt2)
#pragma unroll
      for (int ntl = 0; ntl < 2; ++ntl) {
        int h = (wv * 2 + ntl) * 16 + col16;
#pragma unroll
        for (int r = 0; r < 4; ++r) {
          int n = mt2 * 16 + lg * 4 + r;
          dst[n * Hh + h] = (__bf16)ag[mt2][ntl][r];
        }
      }
  } else {
    float* dst = g_agg + (size_t)slice * Nn * Hh;
#pragma unroll
    for (int mt2 = 0; mt2 < 3; ++mt2)
#pragma unroll
      for (int ntl = 0; ntl < 2; ++ntl) {
        int h = (wv * 2 + ntl) * 16 + col16;
#pragma unroll
        for (int r = 0; r < 4; ++r) {
          int n = mt2 * 16 + lg * 4 + r;
          atomicAdd(dst + n * Hh + h, ag[mt2][ntl][r]);
        }
      }
  }
}

// 4 weight matrices [256][256] fp32 -> bf16 MFMA B-fragment-linear
__global__ void prep_frag(const float* __restrict__ mf2_w, const float* __restrict__ at1_w1,
                          const float* __restrict__ at1_w2, __bf16* __restrict__ wfdst) {
  int id = blockIdx.x * 256 + threadIdx.x;  // 32768 total
  int mat = id >> 13, r = id & 8191;
  int kt = r >> 10, q = r & 1023, nt = q >> 6, l = q & 63;
  int row = nt * 16 + (l & 15), col = kt * 32 + (l >> 4) * 8;
  const float* src = (mat == 0) ? mf2_w : (mat == 1) ? (mf2_w + 65536)
                   : (mat == 2) ? at1_w1 : at1_w2;
  const float* p = src + row * 256 + col;
  __bf16* d = wfdst + (size_t)mat * 65536 + ((size_t)(kt * 16 + nt) * 64 + l) * 8;
#pragma unroll
  for (int j = 0; j < 8; ++j) d[j] = (__bf16)p[j];
}

// mf1 (2F=8 -> H=256) as K=32-padded B-frags; bias folded at k=8
__global__ void prep_mf1(const float* __restrict__ mf1_w, const float* __restrict__ mf1_b,
                         __bf16* __restrict__ wfdst) {
  int id = blockIdx.x * 256 + threadIdx.x;  // 2048 total
  int ty = id >> 10, q = id & 1023, ntg = q >> 6, l = q & 63;
  int col = ntg * 16 + (l & 15);
  int k0 = (l >> 4) * 8;
  bf16x8 v;
#pragma unroll
  for (int j = 0; j < 8; ++j) {
    int k = k0 + j;
    float x = (k < 8) ? mf1_w[ty * 2048 + col * 8 + k]
            : (k == 8) ? mf1_b[ty * 256 + col] : 0.f;
    v[j] = (__bf16)x;
  }
  ((bf16x8*)(wfdst + 262144))[id] = v;
}

// rel_rec^T per-tile bf16 A-fragments: rra[tile][kt2(2)][mt2(3)][lane][8]
__global__ void prep_rra(const float* __restrict__ rel_rec, __bf16* __restrict__ rra) {
  int id = blockIdx.x * 256 + threadIdx.x;  // 36*384 = 13824
  if (id >= 13824) return;
  int tile = id / 384, r = id % 384;
  int kt2 = r / 192, r2 = r % 192, mt2 = r2 >> 6, l = r2 & 63;
  int ebase = tile * 64 + kt2 * 32 + (l >> 4) * 8;
  int n = mt2 * 16 + (l & 15);
  bf16x8 v;
#pragma unroll
  for (int j = 0; j < 8; ++j) {
    int e = ebase + j;
    v[j] = (__bf16)((e < Ee) ? rel_rec[(size_t)e * Nn + n] : 0.f);
  }
  ((bf16x8*)rra)[id] = v;
}

// transpose node-side weights (fp32) for coalesced lane reads
__global__ void prep_node(const float* __restrict__ at5_w1, const float* __restrict__ at5_w2,
                          const float* __restrict__ o1_w, const float* __restrict__ o2_w,
                          const float* __restrict__ o3_w, float* __restrict__ ws) {
  int id = blockIdx.x * 256 + threadIdx.x;
  float* T1 = ws;
  float* T2 = T1 + 67600;
  float* To1 = T2 + 67600;
  float* To2 = To1 + 66560;
  float* To3 = To2 + 65536;
  if (id < 67600) { int o = id % 260, k = id / 260; T1[k * 260 + o] = at5_w1[o * 260 + k]; return; }
  id -= 67600;
  if (id < 67600) { int o = id % 260, k = id / 260; T2[k * 260 + o] = at5_w2[o * 260 + k]; return; }
  id -= 67600;
  if (id < 66560) { int o = id & 255, k = id >> 8; To1[k * 256 + o] = o1_w[o * 260 + k]; return; }
  id -= 66560;
  if (id < 65536) { int o = id & 255, k = id >> 8; To2[k * 256 + o] = o2_w[o * 256 + k]; return; }
  id -= 65536;
  if (id < 1024) { int f = id & 3, k = id >> 2; To3[k * 4 + f] = o3_w[f * 256 + k]; }
}

template<int MODE>
__global__ __launch_bounds__(256, 4)
void node_kernel(const float* __restrict__ g_agg, const __bf16* __restrict__ partb,
                 const float* __restrict__ x,
                 const float* __restrict__ T1, const float* __restrict__ T2,
                 const float* __restrict__ To1, const float* __restrict__ To2,
                 const float* __restrict__ To3, const float* __restrict__ at5_b1,
                 const float* __restrict__ at5_b2, const float* __restrict__ at5_g,
                 const float* __restrict__ at5_be, const float* __restrict__ o1_b,
                 const float* __restrict__ o2_b, const float* __restrict__ o3_b,
                 float* __restrict__ out) {
  __shared__ float bufA[12 * 264], bufB[12 * 264], xres[12 * 4];
  const int tid = threadIdx.x;
  const int slice = blockIdx.x >> 2, rg = blockIdx.x & 3;
  const int n0 = rg * 12;
  for (int t = tid; t < 12 * 256; t += 256) {
    int r = t >> 8, h = t & 255;
    float s;
    if (MODE == 1) {
      s = 0.f;
#pragma unroll
      for (int sp = 0; sp < 4; ++sp)
        s += (float)partb[(((size_t)slice * 4 + sp) * Nn + n0 + r) * Hh + h];
    } else {
      s = g_agg[(size_t)slice * 12288 + (size_t)(n0 + r) * 256 + h];
    }
    bufA[r * 264 + h] = s;
  }
  if (tid < 48) {
    int r = tid >> 2, f = tid & 3;
    float v = x[(size_t)slice * 192 + (n0 + r) * 4 + f];
    bufA[r * 264 + 256 + f] = v;
    xres[tid] = v;
  }
  __syncthreads();

  auto layer = [&](const float* WT, const float* bsrc, const float* in, float* outb,
                   int K, int O, int act, const float* gsc, const float* gbe) {
    for (int o = tid; o < O; o += 256) {
      float a[12];
      float bb = bsrc[o];
#pragma unroll
      for (int r = 0; r < 12; ++r) a[r] = bb;
      for (int k = 0; k < K; ++k) {
        float w = WT[k * O + o];
#pragma unroll
        for (int r = 0; r < 12; ++r) a[r] = fmaf(in[r * 264 + k], w, a[r]);
      }
      float scv = 1.f, bev = 0.f;
      if (act == 2) { scv = gsc[o] * BN_RS; bev = gbe[o]; }
#pragma unroll
      for (int r = 0; r < 12; ++r) {
        float v = a[r];
        v = (act == 0) ? fmaxf(v, 0.f) : eluf(v);
        if (act == 2) v = v * scv + bev;
        outb[r * 264 + o] = v;
      }
    }
    __syncthreads();
  };

  layer(T1, at5_b1, bufA, bufB, 260, 260, 1, nullptr, nullptr);
  layer(T2, at5_b2, bufB, bufA, 260, 260, 2, at5_g, at5_be);
  layer(To1, o1_b, bufA, bufB, 260, 256, 0, nullptr, nullptr);
  layer(To2, o2_b, bufB, bufA, 256, 256, 0, nullptr, nullptr);
  if (tid < 48) {
    int r = tid >> 2, f = tid & 3;
    float s = o3_b[f];
    for (int k = 0; k < 256; ++k) s = fmaf(bufA[r * 264 + k], To3[k * 4 + f], s);
    out[(size_t)slice * 192 + (n0 + r) * 4 + f] = xres[tid] + s;
  }
}

extern "C" void kernel_launch(void* const* d_in, const int* in_sizes, int n_in,
                              void* d_out, int out_size, void* d_ws, size_t ws_size,
                              hipStream_t stream) {
  const float* x = (const float*)d_in[0];
  const float* rel_rec = (const float*)d_in[1];
  const float* rel_send = (const float*)d_in[2];
  const float* rel_type = (const float*)d_in[3];
  const float* mf1_w = (const float*)d_in[4];
  const float* mf1_b = (const float*)d_in[5];
  const float* mf2_w = (const float*)d_in[6];
  const float* mf2_b = (const float*)d_in[7];
  const float* at1_w1 = (const float*)d_in[8];
  const float* at1_b1 = (const float*)d_in[9];
  const float* at1_w2 = (const float*)d_in[10];
  const float* at1_b2 = (const float*)d_in[11];
  const float* at1_g = (const float*)d_in[12];
  const float* at1_be = (const float*)d_in[13];
  const float* at5_w1 = (const float*)d_in[14];
  const float* at5_b1 = (const float*)d_in[15];
  const float* at5_w2 = (const float*)d_in[16];
  const float* at5_b2 = (const float*)d_in[17];
  const float* at5_g = (const float*)d_in[18];
  const float* at5_be = (const float*)d_in[19];
  const float* o1_w = (const float*)d_in[20];
  const float* o1_b = (const float*)d_in[21];
  const float* o2_w = (const float*)d_in[22];
  const float* o2_b = (const float*)d_in[23];
  const float* o3_w = (const float*)d_in[24];
  const float* o3_b = (const float*)d_in[25];

  char* ws = (char*)d_ws;
  __bf16* wf = (__bf16*)(ws + WS_WF);
  __bf16* rra = (__bf16*)(ws + WS_RRA);
  float* tnode = (float*)(ws + WS_TN);
  float* g_agg = (float*)(ws + WS_AGG);
  __bf16* partb = (__bf16*)(ws + WS_PB);

  const int mode = (ws_size >= WS_NEED1) ? 1 : 0;

  prep_frag<<<128, 256, 0, stream>>>(mf2_w, at1_w1, at1_w2, wf);
  prep_mf1<<<8, 256, 0, stream>>>(mf1_w, mf1_b, wf);
  prep_rra<<<54, 256, 0, stream>>>(rel_rec, rra);
  prep_node<<<1049, 256, 0, stream>>>(at5_w1, at5_w2, o1_w, o2_w, o3_w, tnode);

  if (mode == 1) {
    hipFuncSetAttribute((const void*)edge_kernel<1>,
                        hipFuncAttributeMaxDynamicSharedMemorySize, LDS_EDGE_BYTES);
    edge_kernel<1><<<BT * 4, 512, LDS_EDGE_BYTES, stream>>>(
        x, rel_rec, rel_send, rel_type, mf2_b, at1_b1, at1_b2,
        at1_g, at1_be, wf, rra, g_agg, partb);
    node_kernel<1><<<256, 256, 0, stream>>>(g_agg, partb, x, tnode, tnode + 67600,
                                            tnode + 135200, tnode + 201760, tnode + 267296,
                                            at5_b1, at5_b2, at5_g, at5_be,
                                            o1_b, o2_b, o3_b, (float*)d_out);
  } else {
    hipMemsetAsync(g_agg, 0, (size_t)BT * Nn * Hh * 4, stream);
    hipFuncSetAttribute((const void*)edge_kernel<0>,
                        hipFuncAttributeMaxDynamicSharedMemorySize, LDS_EDGE_BYTES);
    edge_kernel<0><<<BT * 4, 512, LDS_EDGE_BYTES, stream>>>(
        x, rel_rec, rel_send, rel_type, mf2_b, at1_b1, at1_b2,
        at1_g, at1_be, wf, rra, g_agg, partb);
    node_kernel<0><<<256, 256, 0, stream>>>(g_agg, partb, x, tnode, tnode + 67600,
                                            tnode + 135200, tnode + 201760, tnode + 267296,
                                            at5_b1, at5_b2, at5_g, at5_be,
                                            o1_b, o2_b, o3_b, (float*)d_out);
  }
}